// Round 13
// baseline (561.098 us; speedup 1.0000x reference)
//
#include <hip/hip_runtime.h>
#include <math.h>

// Problem constants
#define BGRAPH 64
#define NNODE  512
#define NTOT   32768        // BGRAPH*NNODE
#define CIN    128
#define HDIM   128
#define EDIM_  5
#define EDGES  524288
#define K1C    256
#define K2C    128

using f32x4 = __attribute__((ext_vector_type(4))) float;
using s16x8 = __attribute__((ext_vector_type(8))) short;

__device__ __forceinline__ short f2bf(float f) {
    union { float f; unsigned u; } v; v.f = f;
    unsigned r = v.u + 0x7fffu + ((v.u >> 16) & 1u);   // RNE
    return (short)(r >> 16);
}
__device__ __forceinline__ float bf2f(short s) {
    union { unsigned u; float f; } v; v.u = ((unsigned)(unsigned short)s) << 16;
    return v.f;
}

// ---------------------------------------------------------------------------
// BatchNorm statistics: 256 blocks, float4 loads, per-block partials
// ---------------------------------------------------------------------------
__global__ __launch_bounds__(256) void bn_stats_kernel(const float* __restrict__ x,
                                                       float* __restrict__ psum,
                                                       float* __restrict__ psq) {
    int tid = threadIdx.x, bid = blockIdx.x;
    long idx0 = (long)bid * 256 + tid;
    float4 s = {0.f, 0.f, 0.f, 0.f}, q = {0.f, 0.f, 0.f, 0.f};
#pragma unroll
    for (int it = 0; it < 16; ++it) {
        float4 v = *(const float4*)(x + (idx0 + (long)it * 65536) * 4);
        s.x += v.x; s.y += v.y; s.z += v.z; s.w += v.w;
        q.x += v.x * v.x; q.y += v.y * v.y; q.z += v.z * v.z; q.w += v.w * v.w;
    }
    __shared__ float ss[128], sq[128];
    if (tid < 128) { ss[tid] = 0.f; sq[tid] = 0.f; }
    __syncthreads();
    int c0 = (tid & 31) * 4;
    atomicAdd(&ss[c0 + 0], s.x); atomicAdd(&ss[c0 + 1], s.y);
    atomicAdd(&ss[c0 + 2], s.z); atomicAdd(&ss[c0 + 3], s.w);
    atomicAdd(&sq[c0 + 0], q.x); atomicAdd(&sq[c0 + 1], q.y);
    atomicAdd(&sq[c0 + 2], q.z); atomicAdd(&sq[c0 + 3], q.w);
    __syncthreads();
    if (tid < 128) {
        psum[bid * 128 + tid] = ss[tid];
        psq[bid * 128 + tid]  = sq[tid];
    }
}

__global__ __launch_bounds__(128) void bn_finalize_kernel(const float* __restrict__ psum,
                                                          const float* __restrict__ psq,
                                                          const float* __restrict__ gamma,
                                                          const float* __restrict__ beta,
                                                          float* __restrict__ scale,
                                                          float* __restrict__ shift) {
    int c = threadIdx.x;
    float s = 0.f, q = 0.f;
    for (int b = 0; b < 256; ++b) { s += psum[b * 128 + c]; q += psq[b * 128 + c]; }
    float mu  = s / (float)NTOT;
    float var = q / (float)NTOT - mu * mu;
    float rstd = rsqrtf(var + 1e-5f);
    float sc = gamma[c] * rstd;
    scale[c] = sc;
    shift[c] = beta[c] - mu * sc;
}

// ---------------------------------------------------------------------------
// Pack Wq|Wk|Wv|Wskip into [128,512] and biases into [512]
// ---------------------------------------------------------------------------
__global__ __launch_bounds__(256) void pack_w4_kernel(const float* __restrict__ Wq, const float* __restrict__ Wk,
                                                      const float* __restrict__ Wv, const float* __restrict__ Ws,
                                                      const float* __restrict__ bq, const float* __restrict__ bk,
                                                      const float* __restrict__ bv, const float* __restrict__ bs,
                                                      float* __restrict__ W4, float* __restrict__ bias4) {
    int i = blockIdx.x * 256 + threadIdx.x;
    if (i < 128 * 512) {
        int k = i / 512, j = i % 512;
        float v;
        if (j < 128)      v = Wq[k * 128 + j];
        else if (j < 256) v = Wk[k * 128 + (j - 128)];
        else if (j < 384) v = Wv[k * 128 + (j - 256)];
        else              v = Ws[k * 128 + (j - 384)];
        W4[i] = v;
    }
    if (i < 512) {
        float v;
        if (i < 128)      v = bq[i];
        else if (i < 256) v = bk[i - 128];
        else if (i < 384) v = bv[i - 256];
        else              v = bs[i - 384];
        bias4[i] = v;
    }
}

// ---------------------------------------------------------------------------
// CSR build: histogram, scan (both arrays in one launch), scatter
// ---------------------------------------------------------------------------
__global__ __launch_bounds__(256) void hist_kernel(const int* __restrict__ ei,
                                                   int* __restrict__ deg_src,
                                                   int* __restrict__ deg_dst) {
    int e = blockIdx.x * 256 + threadIdx.x;
    if (e < EDGES) {
        atomicAdd(&deg_src[ei[e]], 1);
        atomicAdd(&deg_dst[ei[EDGES + e]], 1);
    }
}

__global__ __launch_bounds__(1024) void scan2_kernel(const int* __restrict__ deg_src,
                                                     int* __restrict__ rp_src, int* __restrict__ cur_src,
                                                     const int* __restrict__ deg_dst,
                                                     int* __restrict__ rp_dst, int* __restrict__ cur_dst) {
    const int* deg = blockIdx.x ? deg_dst : deg_src;
    int* rowptr    = blockIdx.x ? rp_dst  : rp_src;
    int* cursor    = blockIdx.x ? cur_dst : cur_src;
    __shared__ int part[1024];
    int tid = threadIdx.x;
    int base = tid * 32;
    int s = 0;
    for (int i = 0; i < 32; ++i) s += deg[base + i];
    part[tid] = s;
    __syncthreads();
    for (int off = 1; off < 1024; off <<= 1) {
        int v = part[tid];
        int add = (tid >= off) ? part[tid - off] : 0;
        __syncthreads();
        part[tid] = v + add;
        __syncthreads();
    }
    int run = (tid == 0) ? 0 : part[tid - 1];
    for (int i = 0; i < 32; ++i) {
        rowptr[base + i] = run;
        cursor[base + i] = run;
        run += deg[base + i];
    }
}

__global__ __launch_bounds__(256) void scatter_kernel(const int* __restrict__ ei,
                                                      int* __restrict__ cur_src, int* __restrict__ cur_dst,
                                                      int* __restrict__ eid_src, int* __restrict__ eid_dst) {
    int e = blockIdx.x * 256 + threadIdx.x;
    if (e < EDGES) {
        int s = ei[e], d = ei[EDGES + e];
        eid_src[atomicAdd(&cur_src[s], 1)] = e;
        eid_dst[atomicAdd(&cur_dst[d], 1)] = e;
    }
}

// ---------------------------------------------------------------------------
// BF16 MFMA GEMM, tile TILE x TILE (128 or 64), BK=32.
//   AU8: A uint8 counts. ATRBF16: TRANS_A bf16 A. ABF16: !TRANS_A bf16 A.
//   BBF16: B already bf16. OBF16: bf16 output. DUAL: concat-K second source.
// ---------------------------------------------------------------------------
template <int TILE, bool TRANS_A, bool AFFINE, bool RELU, bool DUAL,
          bool OBF16, bool AU8, bool BBF16, bool ATRBF16, bool ABF16>
__global__ __launch_bounds__(256) void mgemm(const void* __restrict__ Av,
                                             const void* __restrict__ Bv,
                                             const void* __restrict__ A2v,
                                             const void* __restrict__ B2v,
                                             int Ksplit,
                                             const float* __restrict__ bias,
                                             void* __restrict__ Cv,
                                             const float* __restrict__ scale,
                                             const float* __restrict__ shift,
                                             int M, int Nc, int K,
                                             int lda, int ldb, int ldc,
                                             long sA, long sB, long sC) {
    __shared__ __align__(16) short As[TILE * 40];
    __shared__ __align__(16) short Bs[TILE * 40];
    constexpr int ASZ = AU8 ? 1 : ((ATRBF16 || ABF16) ? 2 : 4);
    constexpr int BSZ = BBF16 ? 2 : 4;
    const char* Abase = (const char*)Av + (long)blockIdx.z * sA * ASZ;
    const char* Bbase = (const char*)Bv + (long)blockIdx.z * sB * BSZ;
    float* C = (float*)Cv + (OBF16 ? 0 : (long)blockIdx.z * sC);
    short* Cs = (short*)Cv + (OBF16 ? (long)blockIdx.z * sC : 0);
    const int m0 = blockIdx.y * TILE, n0 = blockIdx.x * TILE;
    const int tid = threadIdx.x;
    const int lane16 = tid & 15;
    const int quad = (tid & 63) >> 4;
    const int wrow = (tid >> 6) >> 1, wcol = (tid >> 6) & 1;
    constexpr int WT = TILE / 32;

    f32x4 acc[WT][WT] = {};

    for (int k0 = 0; k0 < K; k0 += 32) {
        const char* Au = Abase; const char* Bu = Bbase; int ku = k0;
        if (DUAL && k0 >= Ksplit) { Au = (const char*)A2v; Bu = (const char*)B2v; ku = k0 - Ksplit; }

        if (!TRANS_A) {
#pragma unroll
            for (int p = 0; p < TILE / 32; ++p) {
                int idx = tid + p * 256;
                int row = idx >> 3, c4 = idx & 7;
                short4 o;
                if (AU8) {
                    unsigned u = *(const unsigned*)((const unsigned char*)Au +
                                                    (long)(m0 + row) * lda + ku + c4 * 4);
                    o = make_short4(f2bf((float)(u & 255u)), f2bf((float)((u >> 8) & 255u)),
                                    f2bf((float)((u >> 16) & 255u)), f2bf((float)((u >> 24) & 255u)));
                } else if (ABF16) {
                    o = *(const short4*)((const short*)Au + (long)(m0 + row) * lda + ku + c4 * 4);
                } else {
                    float4 v = *(const float4*)((const float*)Au + (long)(m0 + row) * lda + ku + c4 * 4);
                    if (AFFINE) {
                        int k = ku + c4 * 4;
                        v.x = v.x * scale[k] + shift[k];
                        v.y = v.y * scale[k + 1] + shift[k + 1];
                        v.z = v.z * scale[k + 2] + shift[k + 2];
                        v.w = v.w * scale[k + 3] + shift[k + 3];
                    }
                    o = make_short4(f2bf(v.x), f2bf(v.y), f2bf(v.z), f2bf(v.w));
                }
                *(short4*)&As[row * 40 + c4 * 4] = o;
            }
        } else {
            if (TILE == 128 || tid < 128) {
                int c4 = tid >> 3, g = tid & 7;        // row-group slow, k-group fast
                short* d = &As[(c4 * 4) * 40 + g * 4];
                if (ATRBF16) {
                    const short* src = (const short*)Au + (long)(ku + g * 4) * lda + m0 + c4 * 4;
                    short4 r0 = *(const short4*)(src);
                    short4 r1 = *(const short4*)(src + lda);
                    short4 r2 = *(const short4*)(src + 2 * lda);
                    short4 r3 = *(const short4*)(src + 3 * lda);
                    *(short4*)(d + 0 * 40) = make_short4(r0.x, r1.x, r2.x, r3.x);
                    *(short4*)(d + 1 * 40) = make_short4(r0.y, r1.y, r2.y, r3.y);
                    *(short4*)(d + 2 * 40) = make_short4(r0.z, r1.z, r2.z, r3.z);
                    *(short4*)(d + 3 * 40) = make_short4(r0.w, r1.w, r2.w, r3.w);
                } else {
                    const float* src = (const float*)Au + (long)(ku + g * 4) * lda + m0 + c4 * 4;
                    float4 r0 = *(const float4*)(src);
                    float4 r1 = *(const float4*)(src + lda);
                    float4 r2 = *(const float4*)(src + 2 * lda);
                    float4 r3 = *(const float4*)(src + 3 * lda);
                    *(short4*)(d + 0 * 40) = make_short4(f2bf(r0.x), f2bf(r1.x), f2bf(r2.x), f2bf(r3.x));
                    *(short4*)(d + 1 * 40) = make_short4(f2bf(r0.y), f2bf(r1.y), f2bf(r2.y), f2bf(r3.y));
                    *(short4*)(d + 2 * 40) = make_short4(f2bf(r0.z), f2bf(r1.z), f2bf(r2.z), f2bf(r3.z));
                    *(short4*)(d + 3 * 40) = make_short4(f2bf(r0.w), f2bf(r1.w), f2bf(r2.w), f2bf(r3.w));
                }
            }
        }
        if (TILE == 128 || tid < 128) {
            int c4 = tid >> 3, g = tid & 7;            // n-group slow, k-group fast
            short* d = &Bs[(c4 * 4) * 40 + g * 4];
            if (BBF16) {
                const short* src = (const short*)Bu + (long)(ku + g * 4) * ldb + n0 + c4 * 4;
                short4 r0 = *(const short4*)(src);
                short4 r1 = *(const short4*)(src + ldb);
                short4 r2 = *(const short4*)(src + 2 * ldb);
                short4 r3 = *(const short4*)(src + 3 * ldb);
                *(short4*)(d + 0 * 40) = make_short4(r0.x, r1.x, r2.x, r3.x);
                *(short4*)(d + 1 * 40) = make_short4(r0.y, r1.y, r2.y, r3.y);
                *(short4*)(d + 2 * 40) = make_short4(r0.z, r1.z, r2.z, r3.z);
                *(short4*)(d + 3 * 40) = make_short4(r0.w, r1.w, r2.w, r3.w);
            } else {
                const float* src = (const float*)Bu + (long)(ku + g * 4) * ldb + n0 + c4 * 4;
                float4 r0 = *(const float4*)(src);
                float4 r1 = *(const float4*)(src + ldb);
                float4 r2 = *(const float4*)(src + 2 * ldb);
                float4 r3 = *(const float4*)(src + 3 * ldb);
                *(short4*)(d + 0 * 40) = make_short4(f2bf(r0.x), f2bf(r1.x), f2bf(r2.x), f2bf(r3.x));
                *(short4*)(d + 1 * 40) = make_short4(f2bf(r0.y), f2bf(r1.y), f2bf(r2.y), f2bf(r3.y));
                *(short4*)(d + 2 * 40) = make_short4(f2bf(r0.z), f2bf(r1.z), f2bf(r2.z), f2bf(r3.z));
                *(short4*)(d + 3 * 40) = make_short4(f2bf(r0.w), f2bf(r1.w), f2bf(r2.w), f2bf(r3.w));
            }
        }
        __syncthreads();

        s16x8 af[WT], bf[WT];
#pragma unroll
        for (int t = 0; t < WT; ++t) {
            af[t] = *(const s16x8*)&As[(wrow * (TILE / 2) + t * 16 + lane16) * 40 + quad * 8];
            bf[t] = *(const s16x8*)&Bs[(wcol * (TILE / 2) + t * 16 + lane16) * 40 + quad * 8];
        }
#pragma unroll
        for (int i = 0; i < WT; ++i)
#pragma unroll
            for (int j = 0; j < WT; ++j)
                acc[i][j] = __builtin_amdgcn_mfma_f32_16x16x32_bf16(af[i], bf[j], acc[i][j], 0, 0, 0);
        __syncthreads();
    }

#pragma unroll
    for (int i = 0; i < WT; ++i) {
        int gm = m0 + wrow * (TILE / 2) + i * 16 + quad * 4;
#pragma unroll
        for (int j = 0; j < WT; ++j) {
            int gn = n0 + wcol * (TILE / 2) + j * 16 + lane16;
            float bv = bias ? bias[gn] : 0.f;
#pragma unroll
            for (int r = 0; r < 4; ++r) {
                float val = acc[i][j][r] + bv;
                if (RELU) val = fmaxf(val, 0.f);
                if (OBF16) Cs[(long)(gm + r) * ldc + gn] = f2bf(val);
                else       C[(long)(gm + r) * ldc + gn] = val;
            }
        }
    }
}

// ---------------------------------------------------------------------------
// Fused per-edge attention logits + softmax (no dense S): 16 lanes/dst node.
// q row staged to LDS (padded 132 to avoid 4-way group conflicts); lane t
// computes its edge's full q·k dot (16 independent k-streams per group).
// Outputs raw alpha[pos], linv[node], ea5n[node][5]. XCD-swizzled blocks.
// ---------------------------------------------------------------------------
__global__ __launch_bounds__(256) void attn_fuse_kernel(const int* __restrict__ ei,
                                                        const float* __restrict__ eattr,
                                                        const float* __restrict__ We,
                                                        const int* __restrict__ rp_dst,
                                                        const int* __restrict__ deg_dst,
                                                        const int* __restrict__ eid_dst,
                                                        const short* __restrict__ qkvs,
                                                        float* __restrict__ alpha,
                                                        float* __restrict__ linv,
                                                        float* __restrict__ ea5n) {
    __shared__ float sWe[EDIM_ * 128];             // 2.5 KB
    __shared__ float qs[16][132];                  // 8.25 KB, padded stride
    int g = threadIdx.x >> 4;
    int lane = threadIdx.x & 15;
    // XCD swizzle (match pv_gather): graph's 32 blocks on one XCD
    int b = blockIdx.x;
    int xcd = b & 7, idx = b >> 3;
    int nb = (xcd * 8 + (idx >> 5)) * 32 + (idx & 31);
    int node = nb * 16 + g;
    for (int i = threadIdx.x; i < EDIM_ * 128; i += 256) sWe[i] = We[i];
    // stage this group's q row (fp32) — written/read by same 16-lane group
    {
        s16x8 qv = *(const s16x8*)(qkvs + (long)node * 512 + lane * 8);
#pragma unroll
        for (int j = 0; j < 8; ++j) qs[g][lane * 8 + j] = bf2f(qv[j]);
    }
    __syncthreads();                               // covers sWe (qs is group-local)

    // qw[d] = (q . We[d]) / sqrt(H): per-lane 8-channel partial + butterfly
    float qw[EDIM_];
#pragma unroll
    for (int d = 0; d < EDIM_; ++d) {
        float p = 0.f;
#pragma unroll
        for (int j = 0; j < 8; ++j) p += qs[g][lane * 8 + j] * sWe[d * 128 + lane * 8 + j];
        qw[d] = p;
    }
#pragma unroll
    for (int off = 8; off; off >>= 1)
#pragma unroll
        for (int d = 0; d < EDIM_; ++d) qw[d] += __shfl_xor(qw[d], off);
    const float inv_sqrt_h = 0.08838834764831845f;
#pragma unroll
    for (int d = 0; d < EDIM_; ++d) qw[d] *= inv_sqrt_h;

    int start = rp_dst[node], cnt = deg_dst[node];
    float lsum = 0.f, a5[EDIM_] = {};
    for (int t = lane; t < cnt; t += 16) {
        int e = eid_dst[start + t];
        int src = ei[e];                           // global node id
        // full 128-dim dot: 16 independent 16B k-loads, broadcast q from LDS
        const s16x8* kr = (const s16x8*)(qkvs + (long)src * 512 + 128);
        float dot = 0.f;
#pragma unroll
        for (int c = 0; c < 16; ++c) {
            s16x8 kv = kr[c];
#pragma unroll
            for (int j = 0; j < 8; ++j) dot += bf2f(kv[j]) * qs[g][c * 8 + j];
        }
        float lg = dot * inv_sqrt_h;
        float ea[EDIM_];
#pragma unroll
        for (int d = 0; d < EDIM_; ++d) { ea[d] = eattr[e * EDIM_ + d]; lg += ea[d] * qw[d]; }
        float wv = expf(lg);                       // logits O(1): no max-pass needed
        alpha[start + t] = wv;
        lsum += wv;
#pragma unroll
        for (int d = 0; d < EDIM_; ++d) a5[d] += wv * ea[d];
    }
#pragma unroll
    for (int off = 8; off; off >>= 1) {
        lsum += __shfl_xor(lsum, off);
#pragma unroll
        for (int d = 0; d < EDIM_; ++d) a5[d] += __shfl_xor(a5[d], off);
    }
    float inv = (lsum > 0.f) ? 1.f / lsum : 0.f;
    if (lane == 0) linv[node] = inv;
    if (lane < EDIM_) {
        float v = lane == 0 ? a5[0] : lane == 1 ? a5[1] : lane == 2 ? a5[2]
                : lane == 3 ? a5[3] : a5[4];
        ea5n[node * EDIM_ + lane] = v * inv;
    }
}

// ---------------------------------------------------------------------------
// PV via edge gather: 16 lanes/dst node. Chunked index-prefetch + unrolled
// independent V loads; XCD swizzle for L2-resident V.
// h = relu((Σ alpha·V[src])·linv + ea5n@We + skip), bf16 out.
// ---------------------------------------------------------------------------
__global__ __launch_bounds__(256) void pv_gather_kernel(const short* __restrict__ qkvs,
                                                        const int* __restrict__ ei,
                                                        const float* __restrict__ alpha,
                                                        const float* __restrict__ linv,
                                                        const int* __restrict__ rp_dst,
                                                        const int* __restrict__ deg_dst,
                                                        const int* __restrict__ eid_dst,
                                                        const float* __restrict__ ea5n,
                                                        const float* __restrict__ We,
                                                        short* __restrict__ h) {
    __shared__ float sWe[EDIM_ * 128];
    for (int i = threadIdx.x; i < EDIM_ * 128; i += 256) sWe[i] = We[i];
    __syncthreads();
    int g = threadIdx.x >> 4;
    int lane = threadIdx.x & 15;
    int gbase = (threadIdx.x & 63) & ~15;
    int b = blockIdx.x;
    int xcd = b & 7, idx = b >> 3;
    int nb = (xcd * 8 + (idx >> 5)) * 32 + (idx & 31);
    int node = nb * 16 + g;
    int start = rp_dst[node], cnt = deg_dst[node];
    float acc[8] = {};
    for (int base = 0; base < cnt; base += 16) {
        int t = base + lane;
        int src = 0; float a = 0.f;
        if (t < cnt) {
            int e = eid_dst[start + t];
            src = ei[e];
            a = alpha[start + t];
        }
        int m = min(16, cnt - base);
        if (m == 16) {
#pragma unroll
            for (int j = 0; j < 16; ++j) {
                int   sj = __shfl(src, gbase + j);
                float aj = __shfl(a,   gbase + j);
                s16x8 v = *(const s16x8*)(qkvs + (long)sj * 512 + 256 + lane * 8);
#pragma unroll
                for (int k = 0; k < 8; ++k) acc[k] += aj * bf2f(v[k]);
            }
        } else {
            for (int j = 0; j < m; ++j) {
                int   sj = __shfl(src, gbase + j);
                float aj = __shfl(a,   gbase + j);
                s16x8 v = *(const s16x8*)(qkvs + (long)sj * 512 + 256 + lane * 8);
#pragma unroll
                for (int k = 0; k < 8; ++k) acc[k] += aj * bf2f(v[k]);
            }
        }
    }
    float inv = linv[node];
    float e5[EDIM_];
#pragma unroll
    for (int d = 0; d < EDIM_; ++d) e5[d] = ea5n[node * EDIM_ + d];
    s16x8 sk = *(const s16x8*)(qkvs + (long)node * 512 + 384 + lane * 8);
    s16x8 o;
#pragma unroll
    for (int j = 0; j < 8; ++j) {
        float ec = 0.f;
#pragma unroll
        for (int d = 0; d < EDIM_; ++d) ec += e5[d] * sWe[d * 128 + lane * 8 + j];
        float val = acc[j] * inv + ec + bf2f(sk[j]);
        o[j] = f2bf(fmaxf(val, 0.f));
    }
    *(s16x8*)(h + (long)node * 128 + lane * 8) = o;
}

// ---------------------------------------------------------------------------
// Dense adjacency count build (uint8 per (src,dst)), by src-CSR.
// ---------------------------------------------------------------------------
__global__ __launch_bounds__(256) void adense_kernel(const int* __restrict__ ei,
                                                     const int* __restrict__ rp_src,
                                                     const int* __restrict__ deg_src,
                                                     const int* __restrict__ eid_src,
                                                     unsigned char* __restrict__ Adense) {
    __shared__ int rows[16][512];
    int g = threadIdx.x >> 4;
    int lane = threadIdx.x & 15;
    int node = blockIdx.x * 16 + g;
    int* row = rows[g];
    for (int i = lane; i < 512; i += 16) row[i] = 0;
    int start = rp_src[node], cnt = deg_src[node];
    for (int t = lane; t < cnt; t += 16) {
        int e = eid_src[start + t];
        int dst = ei[EDGES + e] & 511;
        atomicAdd(&row[dst], 1);
    }
    unsigned* Ar = (unsigned*)(Adense + (long)node * 512);
    for (int i = lane; i < 128; i += 16) {
        unsigned p = (unsigned)row[4 * i]
                   | ((unsigned)row[4 * i + 1] << 8)
                   | ((unsigned)row[4 * i + 2] << 16)
                   | ((unsigned)row[4 * i + 3] << 24);
        Ar[i] = p;
    }
}

// ---------------------------------------------------------------------------
// Row-wise softmax; optionally writes bf16 to a separate buffer
// ---------------------------------------------------------------------------
template <int NC, bool OB>
__global__ __launch_bounds__(256) void softmax_kernel(const float* __restrict__ in,
                                                      void* __restrict__ outv) {
    int wave = threadIdx.x >> 6;
    int lane = threadIdx.x & 63;
    int row = blockIdx.x * 4 + wave;
    const float* p = in + (long)row * NC;
    constexpr int PER = NC / 64;
    float v[PER];
    float mx = -INFINITY;
#pragma unroll
    for (int j = 0; j < PER; ++j) { v[j] = p[lane + j * 64]; mx = fmaxf(mx, v[j]); }
#pragma unroll
    for (int off = 32; off; off >>= 1) mx = fmaxf(mx, __shfl_xor(mx, off));
    float sm = 0.f;
#pragma unroll
    for (int j = 0; j < PER; ++j) { v[j] = expf(v[j] - mx); sm += v[j]; }
#pragma unroll
    for (int off = 32; off; off >>= 1) sm += __shfl_xor(sm, off);
    float inv = 1.f / sm;
    if (OB) {
        short* o = (short*)outv + (long)row * NC;
#pragma unroll
        for (int j = 0; j < PER; ++j) o[lane + j * 64] = f2bf(v[j] * inv);
    } else {
        float* o = (float*)outv + (long)row * NC;
#pragma unroll
        for (int j = 0; j < PER; ++j) o[lane + j * 64] = v[j] * inv;
    }
}

// ---------------------------------------------------------------------------
// Pooled-adj normalization
// ---------------------------------------------------------------------------
template <int KC>
__global__ __launch_bounds__(256) void dinv_kernel(const float* __restrict__ adj,
                                                   float* __restrict__ dinv) {
    int wave = threadIdx.x >> 6;
    int lane = threadIdx.x & 63;
    int row = blockIdx.x * 4 + wave;
    int b = row / KC, r = row % KC;
    const float* p = adj + (long)b * KC * KC + (long)r * KC;
    float s = 0.f;
    for (int j = lane; j < KC; j += 64)
        if (j != r) s += p[j];
#pragma unroll
    for (int off = 32; off; off >>= 1) s += __shfl_xor(s, off);
    if (lane == 0) dinv[row] = 1.f / (sqrtf(s) + 1e-15f);
}

template <int KC>
__global__ __launch_bounds__(256) void scale_adj_kernel(float* __restrict__ adj,
                                                        const float* __restrict__ dinv) {
    long i = (long)blockIdx.x * 256 + threadIdx.x;
    int c = (int)(i % KC);
    long t = i / KC;
    int r = (int)(t % KC);
    int b = (int)(t / KC);
    float v = adj[i];
    v = (r == c) ? 0.f : v * dinv[b * KC + r] * dinv[b * KC + c];
    adj[i] = v;
}

// ---------------------------------------------------------------------------
// Readout
// ---------------------------------------------------------------------------
__global__ __launch_bounds__(128) void readout_kernel(const float* __restrict__ xd3,
                                                      const float* __restrict__ W_lin1,
                                                      const float* __restrict__ b_lin1,
                                                      const float* __restrict__ W_ro,
                                                      const float* __restrict__ b_ro,
                                                      float* __restrict__ out) {
    int b = blockIdx.x, t = threadIdx.x;
    __shared__ float g[128], g2[128], wred[2];
    const float* X = xd3 + (long)b * K2C * 128;
    float s = 0.f;
    for (int r = 0; r < K2C; ++r) s += X[r * 128 + t];
    g[t] = s * (1.f / (float)K2C);
    __syncthreads();
    float u = b_lin1[t];
    for (int k = 0; k < 128; ++k) u += g[k] * W_lin1[k * 128 + t];
    g2[t] = fmaxf(u, 0.f);
    __syncthreads();
    float p = g2[t] * W_ro[t];
#pragma unroll
    for (int off = 32; off; off >>= 1) p += __shfl_xor(p, off);
    if ((t & 63) == 0) wred[t >> 6] = p;
    __syncthreads();
    if (t == 0) {
        float tot = wred[0] + wred[1] + b_ro[0];
        out[b] = 1.f / (1.f + expf(-tot));
    }
}

// ---------------------------------------------------------------------------
extern "C" void kernel_launch(void* const* d_in, const int* in_sizes, int n_in,
                              void* d_out, int out_size, void* d_ws, size_t ws_size,
                              hipStream_t stream) {
    const float* x      = (const float*)d_in[0];
    const int*   ei     = (const int*)d_in[1];
    const float* eattr  = (const float*)d_in[2];
    const float* gamma  = (const float*)d_in[4];
    const float* beta   = (const float*)d_in[5];
    const float* Wq     = (const float*)d_in[6];
    const float* bq     = (const float*)d_in[7];
    const float* Wk     = (const float*)d_in[8];
    const float* bk     = (const float*)d_in[9];
    const float* Wv     = (const float*)d_in[10];
    const float* bv     = (const float*)d_in[11];
    const float* We     = (const float*)d_in[12];
    const float* Wskip  = (const float*)d_in[13];
    const float* bskip  = (const float*)d_in[14];
    const float* W_mlp1 = (const float*)d_in[15];
    const float* b_mlp1 = (const float*)d_in[16];
    const float* W2_rel = (const float*)d_in[17];
    const float* b2_rel = (const float*)d_in[18];
    const float* W2_root= (const float*)d_in[19];
    const float* W_mlp2 = (const float*)d_in[20];
    const float* b_mlp2 = (const float*)d_in[21];
    const float* W3_rel = (const float*)d_in[22];
    const float* b3_rel = (const float*)d_in[23];
    const float* W3_root= (const float*)d_in[24];
    const float* W_lin1 = (const float*)d_in[25];
    const float* b_lin1 = (const float*)d_in[26];
    const float* W_ro   = (const float*)d_in[27];
    const float* b_ro   = (const float*)d_in[28];
    float* out = (float*)d_out;

    char* w = (char*)d_ws;
    const size_t MB = 1ull << 20;
    // Workspace (peak 110 MB), lifetime-aliased (S removed; h at [32,40)):
    short* qkvs = (short*)(w + 0);          // [NTOT,512] bf16 32MB
    float* s1f  = (float*)(w + 0);          // [NTOT,256] fp32 32MB
    short* h    = (short*)(w + 32 * MB);    // [NTOT,128] bf16 8MB
    short* T1s  = (short*)(w + 48 * MB);    // [NTOT,256] bf16 16MB
    short* s1b  = (short*)(w + 64 * MB);    // [NTOT,256] bf16 16MB
    unsigned char* Aden = (unsigned char*)(w + 80 * MB);  // [NTOT,512] u8 16MB
    float* tgc2 = (float*)(w + 48 * MB);    // [B,256,128] fp32 8MB
    short* xd2  = (short*)(w + 56 * MB);    // [B,256,128] bf16 4MB
    float* s2f  = (float*)(w + 64 * MB);    // [B,256,128] fp32 8MB
    short* s2b  = (short*)(w + 72 * MB);    // [B,256,128] bf16 4MB
    float* t2   = (float*)(w + 64 * MB);    // [B,256,128] fp32 8MB (over dead s2f)
    float* adj2 = (float*)(w + 0);          // [B,128,128] 4MB
    float* xp2  = (float*)(w + 4 * MB);     // [B,128,128] 4MB
    float* t3   = (float*)(w + 8 * MB);     // [B,128,128] 4MB
    float* xd3  = (float*)(w + 12 * MB);    // [B,128,128] 4MB
    float* adj1 = (float*)(w + 80 * MB);    // [B,256,256] 16MB (over dead Adense)
    float* xp1  = (float*)(w + 96 * MB);    // [B,256,128] 8MB
    float* ea5n = (float*)(w + 96 * MB);    // [NTOT,5] 640KB (dead before xp1)
    float* alpha= (float*)(w + 97 * MB);    // [EDGES] fp32 2MB (dead before xp1)
    float* linv = (float*)(w + 99 * MB);    // [NTOT] fp32 128KB (dead before xp1)
    char* misc  = w + 104 * MB;
    float* W4     = (float*)(misc + 0x00000);
    float* bias4  = (float*)(misc + 0x40000);
    float* scale  = (float*)(misc + 0x41400);
    float* shift  = (float*)(misc + 0x41600);
    float* dinv1  = (float*)(misc + 0x42000);
    float* dinv2  = (float*)(misc + 0x52000);
    int* deg_src  = (int*)(misc + 0x60000);
    int* deg_dst  = (int*)(misc + 0x80000);
    int* rp_src   = (int*)(misc + 0xA0000);
    int* rp_dst   = (int*)(misc + 0xC0000);
    int* cur_src  = (int*)(misc + 0xE0000);
    int* cur_dst  = (int*)(misc + 0x100000);
    int* eid_src  = (int*)(misc + 0x120000);
    int* eid_dst  = (int*)(misc + 0x320000);
    float* psum   = (float*)(misc + 0x520000);
    float* psq    = (float*)(misc + 0x540000);

    hipMemsetAsync(deg_src, 0, 2 * NTOT * sizeof(int), stream);

    // 1. BatchNorm affine params
    bn_stats_kernel<<<256, 256, 0, stream>>>(x, psum, psq);
    bn_finalize_kernel<<<1, 128, 0, stream>>>(psum, psq, gamma, beta, scale, shift);

    // 2. Pack fused qkvs weights
    pack_w4_kernel<<<256, 256, 0, stream>>>(Wq, Wk, Wv, Wskip, bq, bk, bv, bskip, W4, bias4);

    // 3. CSR by src and dst
    hist_kernel<<<EDGES / 256, 256, 0, stream>>>(ei, deg_src, deg_dst);
    scan2_kernel<<<2, 1024, 0, stream>>>(deg_src, rp_src, cur_src, deg_dst, rp_dst, cur_dst);
    scatter_kernel<<<EDGES / 256, 256, 0, stream>>>(ei, cur_src, cur_dst, eid_src, eid_dst);

    // 4. qkvs(bf16) = BN(x) @ [Wq|Wk|Wv|Wskip] + biases
    mgemm<128, false, true, false, false, true, false, false, false, false>
        <<<dim3(4, 256, 1), 256, 0, stream>>>(
        x, W4, nullptr, nullptr, 0, bias4, qkvs, scale, shift,
        NTOT, 512, 128, 128, 512, 512, 0, 0, 0);

    // 5. Fused per-edge logits + softmax (no dense S): alpha + linv + ea5n
    attn_fuse_kernel<<<NTOT / 16, 256, 0, stream>>>(
        ei, eattr, We, rp_dst, deg_dst, eid_dst, qkvs, alpha, linv, ea5n);

    // 6. h(bf16) = relu(gatherPV + ea5n@We + skip) ; build Adense
    pv_gather_kernel<<<NTOT / 16, 256, 0, stream>>>(
        qkvs, ei, alpha, linv, rp_dst, deg_dst, eid_dst, ea5n, We, h);
    adense_kernel<<<NTOT / 16, 256, 0, stream>>>(ei, rp_src, deg_src, eid_src, Aden);

    // 7. s1f = h @ W_mlp1 + b ; s1b(bf16) = softmax(s1f)
    mgemm<128, false, false, false, false, false, false, false, false, true>
        <<<dim3(2, 256, 1), 256, 0, stream>>>(
        h, W_mlp1, nullptr, nullptr, 0, b_mlp1, s1f, nullptr, nullptr,
        NTOT, K1C, 128, 128, K1C, K1C, 0, 0, 0);
    softmax_kernel<K1C, true><<<NTOT / 4, 256, 0, stream>>>(s1f, s1b);

    // 8. T1(bf16) = Adense(u8) @ s1b(bf16) — 128-tile (deep K, 512 blocks)
    mgemm<128, false, false, false, false, true, true, true, false, false>
        <<<dim3(2, 4, BGRAPH), 256, 0, stream>>>(
        Aden, s1b, nullptr, nullptr, 0, nullptr, T1s, nullptr, nullptr,
        NNODE, K1C, NNODE, NNODE, K1C, K1C,
        (long)NNODE * NNODE, (long)NNODE * K1C, (long)NNODE * K1C);

    // 9. adj1 = s1b^T T1s — 128-tile ; xp1 = s1b^T h (64-tile)
    mgemm<128, true, false, false, false, false, false, true, true, false>
        <<<dim3(2, 2, BGRAPH), 256, 0, stream>>>(
        s1b, T1s, nullptr, nullptr, 0, nullptr, adj1, nullptr, nullptr,
        K1C, K1C, NNODE, K1C, K1C, K1C,
        (long)NNODE * K1C, (long)NNODE * K1C, (long)K1C * K1C);
    mgemm<64, true, false, false, false, false, false, true, true, false>
        <<<dim3(2, 4, BGRAPH), 256, 0, stream>>>(
        s1b, h, nullptr, nullptr, 0, nullptr, xp1, nullptr, nullptr,
        K1C, 128, NNODE, K1C, 128, 128,
        (long)NNODE * K1C, (long)NNODE * 128, (long)K1C * 128);

    // 10. Normalize adj1
    dinv_kernel<K1C><<<(BGRAPH * K1C) / 4, 256, 0, stream>>>(adj1, dinv1);
    scale_adj_kernel<K1C><<<(BGRAPH * K1C * K1C) / 256, 256, 0, stream>>>(adj1, dinv1);

    // 11. GraphConv2: tgc2 = adj1@xp1 ; xd2(bf16) = relu([tgc2|xp1]@[W2_rel;W2_root]+b)
    mgemm<64, false, false, false, false, false, false, false, false, false>
        <<<dim3(2, 4, BGRAPH), 256, 0, stream>>>(
        adj1, xp1, nullptr, nullptr, 0, nullptr, tgc2, nullptr, nullptr,
        K1C, 128, K1C, K1C, 128, 128,
        (long)K1C * K1C, (long)K1C * 128, (long)K1C * 128);
    mgemm<64, false, false, true, true, true, false, false, false, false>
        <<<dim3(2, 256, 1), 256, 0, stream>>>(
        tgc2, W2_rel, xp1, W2_root, 128, b2_rel, xd2, nullptr, nullptr,
        BGRAPH * K1C, 128, 256, 128, 128, 128, 0, 0, 0);

    // 12. s2f = xd2 @ W_mlp2 + b ; s2b(bf16) = softmax(s2f)
    mgemm<64, false, false, false, false, false, false, false, false, true>
        <<<dim3(2, 256, 1), 256, 0, stream>>>(
        xd2, W_mlp2, nullptr, nullptr, 0, b_mlp2, s2f, nullptr, nullptr,
        BGRAPH * K1C, K2C, 128, 128, K2C, K2C, 0, 0, 0);
    softmax_kernel<K2C, true><<<(BGRAPH * K1C) / 4, 256, 0, stream>>>(s2f, s2b);

    // 13. Pool2: t2 = adj1@s2b ; adj2 = s2b^T t2 ; xp2 = s2b^T xd2
    mgemm<64, false, false, false, false, false, false, true, false, false>
        <<<dim3(2, 4, BGRAPH), 256, 0, stream>>>(
        adj1, s2b, nullptr, nullptr, 0, nullptr, t2, nullptr, nullptr,
        K1C, K2C, K1C, K1C, K2C, K2C,
        (long)K1C * K1C, (long)K1C * K2C, (long)K1C * K2C);
    mgemm<64, true, false, false, false, false, false, false, true, false>
        <<<dim3(2, 2, BGRAPH), 256, 0, stream>>>(
        s2b, t2, nullptr, nullptr, 0, nullptr, adj2, nullptr, nullptr,
        K2C, K2C, K1C, K2C, K2C, K2C,
        (long)K1C * K2C, (long)K1C * K2C, (long)K2C * K2C);
    mgemm<64, true, false, false, false, false, false, true, true, false>
        <<<dim3(2, 2, BGRAPH), 256, 0, stream>>>(
        s2b, xd2, nullptr, nullptr, 0, nullptr, xp2, nullptr, nullptr,
        K2C, 128, K1C, K2C, 128, 128,
        (long)K1C * K2C, (long)K1C * 128, (long)K2C * 128);

    // 14. Normalize adj2
    dinv_kernel<K2C><<<(BGRAPH * K2C) / 4, 256, 0, stream>>>(adj2, dinv2);
    scale_adj_kernel<K2C><<<(BGRAPH * K2C * K2C) / 256, 256, 0, stream>>>(adj2, dinv2);

    // 15. GraphConv3: t3 = adj2@xp2 ; xd3 = [t3|xp2]@[W3_rel;W3_root] + b
    mgemm<64, false, false, false, false, false, false, false, false, false>
        <<<dim3(2, 2, BGRAPH), 256, 0, stream>>>(
        adj2, xp2, nullptr, nullptr, 0, nullptr, t3, nullptr, nullptr,
        K2C, 128, K2C, K2C, 128, 128,
        (long)K2C * K2C, (long)K2C * 128, (long)K2C * 128);
    mgemm<64, false, false, false, true, false, false, false, false, false>
        <<<dim3(2, 128, 1), 256, 0, stream>>>(
        t3, W3_rel, xp2, W3_root, 128, b3_rel, xd3, nullptr, nullptr,
        BGRAPH * K2C, 128, 256, 128, 128, 128, 0, 0, 0);

    // 16. Readout
    readout_kernel<<<BGRAPH, 128, 0, stream>>>(xd3, W_lin1, b_lin1, W_ro, b_ro, out);

    (void)in_sizes; (void)n_in; (void)out_size; (void)ws_size;
}

// Round 14
// 554.794 us; speedup vs baseline: 1.0114x; 1.0114x over previous
//
#include <hip/hip_runtime.h>
#include <math.h>

// Problem constants
#define BGRAPH 64
#define NNODE  512
#define NTOT   32768        // BGRAPH*NNODE
#define CIN    128
#define HDIM   128
#define EDIM_  5
#define EDGES  524288
#define K1C    256
#define K2C    128

using f32x4 = __attribute__((ext_vector_type(4))) float;
using s16x8 = __attribute__((ext_vector_type(8))) short;

__device__ __forceinline__ short f2bf(float f) {
    union { float f; unsigned u; } v; v.f = f;
    unsigned r = v.u + 0x7fffu + ((v.u >> 16) & 1u);   // RNE
    return (short)(r >> 16);
}
__device__ __forceinline__ float bf2f(short s) {
    union { unsigned u; float f; } v; v.u = ((unsigned)(unsigned short)s) << 16;
    return v.f;
}

// ---------------------------------------------------------------------------
// BatchNorm statistics: 256 blocks, float4 loads, per-block partials
// ---------------------------------------------------------------------------
__global__ __launch_bounds__(256) void bn_stats_kernel(const float* __restrict__ x,
                                                       float* __restrict__ psum,
                                                       float* __restrict__ psq) {
    int tid = threadIdx.x, bid = blockIdx.x;
    long idx0 = (long)bid * 256 + tid;
    float4 s = {0.f, 0.f, 0.f, 0.f}, q = {0.f, 0.f, 0.f, 0.f};
#pragma unroll
    for (int it = 0; it < 16; ++it) {
        float4 v = *(const float4*)(x + (idx0 + (long)it * 65536) * 4);
        s.x += v.x; s.y += v.y; s.z += v.z; s.w += v.w;
        q.x += v.x * v.x; q.y += v.y * v.y; q.z += v.z * v.z; q.w += v.w * v.w;
    }
    __shared__ float ss[128], sq[128];
    if (tid < 128) { ss[tid] = 0.f; sq[tid] = 0.f; }
    __syncthreads();
    int c0 = (tid & 31) * 4;
    atomicAdd(&ss[c0 + 0], s.x); atomicAdd(&ss[c0 + 1], s.y);
    atomicAdd(&ss[c0 + 2], s.z); atomicAdd(&ss[c0 + 3], s.w);
    atomicAdd(&sq[c0 + 0], q.x); atomicAdd(&sq[c0 + 1], q.y);
    atomicAdd(&sq[c0 + 2], q.z); atomicAdd(&sq[c0 + 3], q.w);
    __syncthreads();
    if (tid < 128) {
        psum[bid * 128 + tid] = ss[tid];
        psq[bid * 128 + tid]  = sq[tid];
    }
}

__global__ __launch_bounds__(128) void bn_finalize_kernel(const float* __restrict__ psum,
                                                          const float* __restrict__ psq,
                                                          const float* __restrict__ gamma,
                                                          const float* __restrict__ beta,
                                                          float* __restrict__ scale,
                                                          float* __restrict__ shift) {
    int c = threadIdx.x;
    float s = 0.f, q = 0.f;
    for (int b = 0; b < 256; ++b) { s += psum[b * 128 + c]; q += psq[b * 128 + c]; }
    float mu  = s / (float)NTOT;
    float var = q / (float)NTOT - mu * mu;
    float rstd = rsqrtf(var + 1e-5f);
    float sc = gamma[c] * rstd;
    scale[c] = sc;
    shift[c] = beta[c] - mu * sc;
}

// ---------------------------------------------------------------------------
// Pack Wq|Wk|Wv|Wskip into [128,512] and biases into [512]
// ---------------------------------------------------------------------------
__global__ __launch_bounds__(256) void pack_w4_kernel(const float* __restrict__ Wq, const float* __restrict__ Wk,
                                                      const float* __restrict__ Wv, const float* __restrict__ Ws,
                                                      const float* __restrict__ bq, const float* __restrict__ bk,
                                                      const float* __restrict__ bv, const float* __restrict__ bs,
                                                      float* __restrict__ W4, float* __restrict__ bias4) {
    int i = blockIdx.x * 256 + threadIdx.x;
    if (i < 128 * 512) {
        int k = i / 512, j = i % 512;
        float v;
        if (j < 128)      v = Wq[k * 128 + j];
        else if (j < 256) v = Wk[k * 128 + (j - 128)];
        else if (j < 384) v = Wv[k * 128 + (j - 256)];
        else              v = Ws[k * 128 + (j - 384)];
        W4[i] = v;
    }
    if (i < 512) {
        float v;
        if (i < 128)      v = bq[i];
        else if (i < 256) v = bk[i - 128];
        else if (i < 384) v = bv[i - 256];
        else              v = bs[i - 384];
        bias4[i] = v;
    }
}

// ---------------------------------------------------------------------------
// CSR build: histogram, scan (both arrays in one launch), scatter
// ---------------------------------------------------------------------------
__global__ __launch_bounds__(256) void hist_kernel(const int* __restrict__ ei,
                                                   int* __restrict__ deg_src,
                                                   int* __restrict__ deg_dst) {
    int e = blockIdx.x * 256 + threadIdx.x;
    if (e < EDGES) {
        atomicAdd(&deg_src[ei[e]], 1);
        atomicAdd(&deg_dst[ei[EDGES + e]], 1);
    }
}

__global__ __launch_bounds__(1024) void scan2_kernel(const int* __restrict__ deg_src,
                                                     int* __restrict__ rp_src, int* __restrict__ cur_src,
                                                     const int* __restrict__ deg_dst,
                                                     int* __restrict__ rp_dst, int* __restrict__ cur_dst) {
    const int* deg = blockIdx.x ? deg_dst : deg_src;
    int* rowptr    = blockIdx.x ? rp_dst  : rp_src;
    int* cursor    = blockIdx.x ? cur_dst : cur_src;
    __shared__ int part[1024];
    int tid = threadIdx.x;
    int base = tid * 32;
    int s = 0;
    for (int i = 0; i < 32; ++i) s += deg[base + i];
    part[tid] = s;
    __syncthreads();
    for (int off = 1; off < 1024; off <<= 1) {
        int v = part[tid];
        int add = (tid >= off) ? part[tid - off] : 0;
        __syncthreads();
        part[tid] = v + add;
        __syncthreads();
    }
    int run = (tid == 0) ? 0 : part[tid - 1];
    for (int i = 0; i < 32; ++i) {
        rowptr[base + i] = run;
        cursor[base + i] = run;
        run += deg[base + i];
    }
}

__global__ __launch_bounds__(256) void scatter_kernel(const int* __restrict__ ei,
                                                      int* __restrict__ cur_src, int* __restrict__ cur_dst,
                                                      int* __restrict__ eid_src, int* __restrict__ eid_dst) {
    int e = blockIdx.x * 256 + threadIdx.x;
    if (e < EDGES) {
        int s = ei[e], d = ei[EDGES + e];
        eid_src[atomicAdd(&cur_src[s], 1)] = e;
        eid_dst[atomicAdd(&cur_dst[d], 1)] = e;
    }
}

// ---------------------------------------------------------------------------
// BF16 MFMA GEMM, tile TILE x TILE (128 or 64), BK=32.
//   AU8: A uint8 counts. ATRBF16: TRANS_A bf16 A. ABF16: !TRANS_A bf16 A.
//   BBF16: B already bf16. OBF16: bf16 output. DUAL: concat-K second source.
// 128-tile for deep-K GEMMs (16 MFMA/wave/K-step); 64-tile for small ones.
// Transpose-stage map (c4=tid>>3 slow, g=tid&7 fast) keeps write conflicts 4-way.
// ---------------------------------------------------------------------------
template <int TILE, bool TRANS_A, bool AFFINE, bool RELU, bool DUAL,
          bool OBF16, bool AU8, bool BBF16, bool ATRBF16, bool ABF16>
__global__ __launch_bounds__(256) void mgemm(const void* __restrict__ Av,
                                             const void* __restrict__ Bv,
                                             const void* __restrict__ A2v,
                                             const void* __restrict__ B2v,
                                             int Ksplit,
                                             const float* __restrict__ bias,
                                             void* __restrict__ Cv,
                                             const float* __restrict__ scale,
                                             const float* __restrict__ shift,
                                             int M, int Nc, int K,
                                             int lda, int ldb, int ldc,
                                             long sA, long sB, long sC) {
    __shared__ __align__(16) short As[TILE * 40];
    __shared__ __align__(16) short Bs[TILE * 40];
    constexpr int ASZ = AU8 ? 1 : ((ATRBF16 || ABF16) ? 2 : 4);
    constexpr int BSZ = BBF16 ? 2 : 4;
    const char* Abase = (const char*)Av + (long)blockIdx.z * sA * ASZ;
    const char* Bbase = (const char*)Bv + (long)blockIdx.z * sB * BSZ;
    float* C = (float*)Cv + (OBF16 ? 0 : (long)blockIdx.z * sC);
    short* Cs = (short*)Cv + (OBF16 ? (long)blockIdx.z * sC : 0);
    const int m0 = blockIdx.y * TILE, n0 = blockIdx.x * TILE;
    const int tid = threadIdx.x;
    const int lane16 = tid & 15;
    const int quad = (tid & 63) >> 4;
    const int wrow = (tid >> 6) >> 1, wcol = (tid >> 6) & 1;
    constexpr int WT = TILE / 32;

    f32x4 acc[WT][WT] = {};

    for (int k0 = 0; k0 < K; k0 += 32) {
        const char* Au = Abase; const char* Bu = Bbase; int ku = k0;
        if (DUAL && k0 >= Ksplit) { Au = (const char*)A2v; Bu = (const char*)B2v; ku = k0 - Ksplit; }

        if (!TRANS_A) {
#pragma unroll
            for (int p = 0; p < TILE / 32; ++p) {
                int idx = tid + p * 256;
                int row = idx >> 3, c4 = idx & 7;
                short4 o;
                if (AU8) {
                    unsigned u = *(const unsigned*)((const unsigned char*)Au +
                                                    (long)(m0 + row) * lda + ku + c4 * 4);
                    o = make_short4(f2bf((float)(u & 255u)), f2bf((float)((u >> 8) & 255u)),
                                    f2bf((float)((u >> 16) & 255u)), f2bf((float)((u >> 24) & 255u)));
                } else if (ABF16) {
                    o = *(const short4*)((const short*)Au + (long)(m0 + row) * lda + ku + c4 * 4);
                } else {
                    float4 v = *(const float4*)((const float*)Au + (long)(m0 + row) * lda + ku + c4 * 4);
                    if (AFFINE) {
                        int k = ku + c4 * 4;
                        v.x = v.x * scale[k] + shift[k];
                        v.y = v.y * scale[k + 1] + shift[k + 1];
                        v.z = v.z * scale[k + 2] + shift[k + 2];
                        v.w = v.w * scale[k + 3] + shift[k + 3];
                    }
                    o = make_short4(f2bf(v.x), f2bf(v.y), f2bf(v.z), f2bf(v.w));
                }
                *(short4*)&As[row * 40 + c4 * 4] = o;
            }
        } else {
            if (TILE == 128 || tid < 128) {
                int c4 = tid >> 3, g = tid & 7;        // row-group slow, k-group fast
                short* d = &As[(c4 * 4) * 40 + g * 4];
                if (ATRBF16) {
                    const short* src = (const short*)Au + (long)(ku + g * 4) * lda + m0 + c4 * 4;
                    short4 r0 = *(const short4*)(src);
                    short4 r1 = *(const short4*)(src + lda);
                    short4 r2 = *(const short4*)(src + 2 * lda);
                    short4 r3 = *(const short4*)(src + 3 * lda);
                    *(short4*)(d + 0 * 40) = make_short4(r0.x, r1.x, r2.x, r3.x);
                    *(short4*)(d + 1 * 40) = make_short4(r0.y, r1.y, r2.y, r3.y);
                    *(short4*)(d + 2 * 40) = make_short4(r0.z, r1.z, r2.z, r3.z);
                    *(short4*)(d + 3 * 40) = make_short4(r0.w, r1.w, r2.w, r3.w);
                } else {
                    const float* src = (const float*)Au + (long)(ku + g * 4) * lda + m0 + c4 * 4;
                    float4 r0 = *(const float4*)(src);
                    float4 r1 = *(const float4*)(src + lda);
                    float4 r2 = *(const float4*)(src + 2 * lda);
                    float4 r3 = *(const float4*)(src + 3 * lda);
                    *(short4*)(d + 0 * 40) = make_short4(f2bf(r0.x), f2bf(r1.x), f2bf(r2.x), f2bf(r3.x));
                    *(short4*)(d + 1 * 40) = make_short4(f2bf(r0.y), f2bf(r1.y), f2bf(r2.y), f2bf(r3.y));
                    *(short4*)(d + 2 * 40) = make_short4(f2bf(r0.z), f2bf(r1.z), f2bf(r2.z), f2bf(r3.z));
                    *(short4*)(d + 3 * 40) = make_short4(f2bf(r0.w), f2bf(r1.w), f2bf(r2.w), f2bf(r3.w));
                }
            }
        }
        if (TILE == 128 || tid < 128) {
            int c4 = tid >> 3, g = tid & 7;            // n-group slow, k-group fast
            short* d = &Bs[(c4 * 4) * 40 + g * 4];
            if (BBF16) {
                const short* src = (const short*)Bu + (long)(ku + g * 4) * ldb + n0 + c4 * 4;
                short4 r0 = *(const short4*)(src);
                short4 r1 = *(const short4*)(src + ldb);
                short4 r2 = *(const short4*)(src + 2 * ldb);
                short4 r3 = *(const short4*)(src + 3 * ldb);
                *(short4*)(d + 0 * 40) = make_short4(r0.x, r1.x, r2.x, r3.x);
                *(short4*)(d + 1 * 40) = make_short4(r0.y, r1.y, r2.y, r3.y);
                *(short4*)(d + 2 * 40) = make_short4(r0.z, r1.z, r2.z, r3.z);
                *(short4*)(d + 3 * 40) = make_short4(r0.w, r1.w, r2.w, r3.w);
            } else {
                const float* src = (const float*)Bu + (long)(ku + g * 4) * ldb + n0 + c4 * 4;
                float4 r0 = *(const float4*)(src);
                float4 r1 = *(const float4*)(src + ldb);
                float4 r2 = *(const float4*)(src + 2 * ldb);
                float4 r3 = *(const float4*)(src + 3 * ldb);
                *(short4*)(d + 0 * 40) = make_short4(f2bf(r0.x), f2bf(r1.x), f2bf(r2.x), f2bf(r3.x));
                *(short4*)(d + 1 * 40) = make_short4(f2bf(r0.y), f2bf(r1.y), f2bf(r2.y), f2bf(r3.y));
                *(short4*)(d + 2 * 40) = make_short4(f2bf(r0.z), f2bf(r1.z), f2bf(r2.z), f2bf(r3.z));
                *(short4*)(d + 3 * 40) = make_short4(f2bf(r0.w), f2bf(r1.w), f2bf(r2.w), f2bf(r3.w));
            }
        }
        __syncthreads();

        s16x8 af[WT], bf[WT];
#pragma unroll
        for (int t = 0; t < WT; ++t) {
            af[t] = *(const s16x8*)&As[(wrow * (TILE / 2) + t * 16 + lane16) * 40 + quad * 8];
            bf[t] = *(const s16x8*)&Bs[(wcol * (TILE / 2) + t * 16 + lane16) * 40 + quad * 8];
        }
#pragma unroll
        for (int i = 0; i < WT; ++i)
#pragma unroll
            for (int j = 0; j < WT; ++j)
                acc[i][j] = __builtin_amdgcn_mfma_f32_16x16x32_bf16(af[i], bf[j], acc[i][j], 0, 0, 0);
        __syncthreads();
    }

#pragma unroll
    for (int i = 0; i < WT; ++i) {
        int gm = m0 + wrow * (TILE / 2) + i * 16 + quad * 4;
#pragma unroll
        for (int j = 0; j < WT; ++j) {
            int gn = n0 + wcol * (TILE / 2) + j * 16 + lane16;
            float bv = bias ? bias[gn] : 0.f;
#pragma unroll
            for (int r = 0; r < 4; ++r) {
                float val = acc[i][j][r] + bv;
                if (RELU) val = fmaxf(val, 0.f);
                if (OBF16) Cs[(long)(gm + r) * ldc + gn] = f2bf(val);
                else       C[(long)(gm + r) * ldc + gn] = val;
            }
        }
    }
}

// ---------------------------------------------------------------------------
// BF16-input MFMA GEMM (TRANS_B — used for QK^T): C = scale*(A@B^T)
// ---------------------------------------------------------------------------
template <bool OBF16>
__global__ __launch_bounds__(256) void bgemm(const short* __restrict__ A,
                                             const short* __restrict__ B,
                                             void* __restrict__ Cv,
                                             float outscale,
                                             int M, int Nc, int K,
                                             int lda, int ldb, int ldc,
                                             long sA, long sB, long sC) {
    __shared__ __align__(16) short As[128 * 40];
    __shared__ __align__(16) short Bs[128 * 40];
    const int z = blockIdx.z;
    A += (long)z * sA;
    B += (long)z * sB;
    float* C = (float*)Cv + (OBF16 ? 0 : (long)z * sC);
    short* Cs = (short*)Cv + (OBF16 ? (long)z * sC : 0);
    const int m0 = blockIdx.y * 128, n0 = blockIdx.x * 128;
    const int tid = threadIdx.x;
    const int lane16 = tid & 15;
    const int quad = (tid & 63) >> 4;
    const int wrow = (tid >> 6) >> 1, wcol = (tid >> 6) & 1;

    f32x4 acc[4][4] = {};

    for (int k0 = 0; k0 < K; k0 += 32) {
#pragma unroll
        for (int p = 0; p < 2; ++p) {
            int u = tid + p * 256;
            int row = u >> 2, g = u & 3;
            *(s16x8*)&As[row * 40 + g * 8] =
                *(const s16x8*)(A + (long)(m0 + row) * lda + k0 + g * 8);
        }
#pragma unroll
        for (int p = 0; p < 2; ++p) {
            int u = tid + p * 256;
            int row = u >> 2, g = u & 3;
            *(s16x8*)&Bs[row * 40 + g * 8] =
                *(const s16x8*)(B + (long)(n0 + row) * ldb + k0 + g * 8);
        }
        __syncthreads();

        s16x8 af[4], bf[4];
#pragma unroll
        for (int t = 0; t < 4; ++t) {
            af[t] = *(const s16x8*)&As[(wrow * 64 + t * 16 + lane16) * 40 + quad * 8];
            bf[t] = *(const s16x8*)&Bs[(wcol * 64 + t * 16 + lane16) * 40 + quad * 8];
        }
#pragma unroll
        for (int i = 0; i < 4; ++i)
#pragma unroll
            for (int j = 0; j < 4; ++j)
                acc[i][j] = __builtin_amdgcn_mfma_f32_16x16x32_bf16(af[i], bf[j], acc[i][j], 0, 0, 0);
        __syncthreads();
    }

#pragma unroll
    for (int i = 0; i < 4; ++i) {
        int gm = m0 + wrow * 64 + i * 16 + quad * 4;
#pragma unroll
        for (int j = 0; j < 4; ++j) {
            int gn = n0 + wcol * 64 + j * 16 + lane16;
#pragma unroll
            for (int r = 0; r < 4; ++r) {
                float val = acc[i][j][r] * outscale;
                if (OBF16) Cs[(long)(gm + r) * ldc + gn] = f2bf(val);
                else       C[(long)(gm + r) * ldc + gn] = val;
            }
        }
    }
}

// ---------------------------------------------------------------------------
// Fused edge-softmax from dense S (bf16): alpha[pos]=w raw, linv, ea5n.
// 16 lanes/dst node; inline qWe; no P matrix.
// ---------------------------------------------------------------------------
__global__ __launch_bounds__(256) void attn_fuse_kernel(const short* __restrict__ S,
                                                        const int* __restrict__ ei,
                                                        const float* __restrict__ eattr,
                                                        const float* __restrict__ We,
                                                        const int* __restrict__ rp_dst,
                                                        const int* __restrict__ deg_dst,
                                                        const int* __restrict__ eid_dst,
                                                        const short* __restrict__ qkvs,
                                                        float* __restrict__ alpha,
                                                        float* __restrict__ linv,
                                                        float* __restrict__ ea5n) {
    __shared__ float sWe[EDIM_ * 128];
    int g = threadIdx.x >> 4;
    int lane = threadIdx.x & 15;
    int node = blockIdx.x * 16 + g;
    for (int i = threadIdx.x; i < EDIM_ * 128; i += 256) sWe[i] = We[i];
    __syncthreads();

    // inline qWe: lane covers channels lane*8..+7, butterfly over 16 lanes
    float qw[EDIM_];
    {
        s16x8 qv = *(const s16x8*)(qkvs + (long)node * 512 + lane * 8);
        float qf[8];
#pragma unroll
        for (int j = 0; j < 8; ++j) qf[j] = bf2f(qv[j]);
#pragma unroll
        for (int d = 0; d < EDIM_; ++d) {
            float p = 0.f;
#pragma unroll
            for (int j = 0; j < 8; ++j) p += qf[j] * sWe[d * 128 + lane * 8 + j];
            qw[d] = p;
        }
#pragma unroll
        for (int off = 8; off; off >>= 1)
#pragma unroll
            for (int d = 0; d < EDIM_; ++d) qw[d] += __shfl_xor(qw[d], off);
#pragma unroll
        for (int d = 0; d < EDIM_; ++d) qw[d] *= 0.08838834764831845f;
    }

    int start = rp_dst[node], cnt = deg_dst[node];
    const short* Srow = S + (long)node * 512;
    float lsum = 0.f, a5[EDIM_] = {};
    for (int t = lane; t < cnt; t += 16) {
        int e = eid_dst[start + t];
        int src = ei[e] & 511;
        float lg = bf2f(Srow[src]);
        float ea[EDIM_];
#pragma unroll
        for (int d = 0; d < EDIM_; ++d) { ea[d] = eattr[e * EDIM_ + d]; lg += ea[d] * qw[d]; }
        float wv = expf(lg);                       // logits O(1): no max-pass needed
        alpha[start + t] = wv;
        lsum += wv;
#pragma unroll
        for (int d = 0; d < EDIM_; ++d) a5[d] += wv * ea[d];
    }
#pragma unroll
    for (int off = 8; off; off >>= 1) {
        lsum += __shfl_xor(lsum, off);
#pragma unroll
        for (int d = 0; d < EDIM_; ++d) a5[d] += __shfl_xor(a5[d], off);
    }
    float inv = (lsum > 0.f) ? 1.f / lsum : 0.f;
    if (lane == 0) linv[node] = inv;
    if (lane < EDIM_) {
        float v = lane == 0 ? a5[0] : lane == 1 ? a5[1] : lane == 2 ? a5[2]
                : lane == 3 ? a5[3] : a5[4];
        ea5n[node * EDIM_ + lane] = v * inv;
    }
}

// ---------------------------------------------------------------------------
// PV via edge gather: 16 lanes/dst node. Chunked index-prefetch + unrolled
// independent V loads; XCD swizzle for L2-resident V.
// h = relu((Σ alpha·V[src])·linv + ea5n@We + skip), bf16 out.
// ---------------------------------------------------------------------------
__global__ __launch_bounds__(256) void pv_gather_kernel(const short* __restrict__ qkvs,
                                                        const int* __restrict__ ei,
                                                        const float* __restrict__ alpha,
                                                        const float* __restrict__ linv,
                                                        const int* __restrict__ rp_dst,
                                                        const int* __restrict__ deg_dst,
                                                        const int* __restrict__ eid_dst,
                                                        const float* __restrict__ ea5n,
                                                        const float* __restrict__ We,
                                                        short* __restrict__ h) {
    __shared__ float sWe[EDIM_ * 128];
    for (int i = threadIdx.x; i < EDIM_ * 128; i += 256) sWe[i] = We[i];
    __syncthreads();
    int g = threadIdx.x >> 4;
    int lane = threadIdx.x & 15;
    int gbase = (threadIdx.x & 63) & ~15;
    int b = blockIdx.x;
    int xcd = b & 7, idx = b >> 3;
    int nb = (xcd * 8 + (idx >> 5)) * 32 + (idx & 31);
    int node = nb * 16 + g;
    int start = rp_dst[node], cnt = deg_dst[node];
    float acc[8] = {};
    for (int base = 0; base < cnt; base += 16) {
        int t = base + lane;
        int src = 0; float a = 0.f;
        if (t < cnt) {
            int e = eid_dst[start + t];
            src = ei[e];
            a = alpha[start + t];
        }
        int m = min(16, cnt - base);
        if (m == 16) {
#pragma unroll
            for (int j = 0; j < 16; ++j) {
                int   sj = __shfl(src, gbase + j);
                float aj = __shfl(a,   gbase + j);
                s16x8 v = *(const s16x8*)(qkvs + (long)sj * 512 + 256 + lane * 8);
#pragma unroll
                for (int k = 0; k < 8; ++k) acc[k] += aj * bf2f(v[k]);
            }
        } else {
            for (int j = 0; j < m; ++j) {
                int   sj = __shfl(src, gbase + j);
                float aj = __shfl(a,   gbase + j);
                s16x8 v = *(const s16x8*)(qkvs + (long)sj * 512 + 256 + lane * 8);
#pragma unroll
                for (int k = 0; k < 8; ++k) acc[k] += aj * bf2f(v[k]);
            }
        }
    }
    float inv = linv[node];
    float e5[EDIM_];
#pragma unroll
    for (int d = 0; d < EDIM_; ++d) e5[d] = ea5n[node * EDIM_ + d];
    s16x8 sk = *(const s16x8*)(qkvs + (long)node * 512 + 384 + lane * 8);
    s16x8 o;
#pragma unroll
    for (int j = 0; j < 8; ++j) {
        float ec = 0.f;
#pragma unroll
        for (int d = 0; d < EDIM_; ++d) ec += e5[d] * sWe[d * 128 + lane * 8 + j];
        float val = acc[j] * inv + ec + bf2f(sk[j]);
        o[j] = f2bf(fmaxf(val, 0.f));
    }
    *(s16x8*)(h + (long)node * 128 + lane * 8) = o;
}

// ---------------------------------------------------------------------------
// Dense adjacency count build (uint8 per (src,dst)), by src-CSR.
// ---------------------------------------------------------------------------
__global__ __launch_bounds__(256) void adense_kernel(const int* __restrict__ ei,
                                                     const int* __restrict__ rp_src,
                                                     const int* __restrict__ deg_src,
                                                     const int* __restrict__ eid_src,
                                                     unsigned char* __restrict__ Adense) {
    __shared__ int rows[16][512];
    int g = threadIdx.x >> 4;
    int lane = threadIdx.x & 15;
    int node = blockIdx.x * 16 + g;
    int* row = rows[g];
    for (int i = lane; i < 512; i += 16) row[i] = 0;
    int start = rp_src[node], cnt = deg_src[node];
    for (int t = lane; t < cnt; t += 16) {
        int e = eid_src[start + t];
        int dst = ei[EDGES + e] & 511;
        atomicAdd(&row[dst], 1);
    }
    unsigned* Ar = (unsigned*)(Adense + (long)node * 512);
    for (int i = lane; i < 128; i += 16) {
        unsigned p = (unsigned)row[4 * i]
                   | ((unsigned)row[4 * i + 1] << 8)
                   | ((unsigned)row[4 * i + 2] << 16)
                   | ((unsigned)row[4 * i + 3] << 24);
        Ar[i] = p;
    }
}

// ---------------------------------------------------------------------------
// Row-wise softmax; optionally writes bf16 to a separate buffer
// ---------------------------------------------------------------------------
template <int NC, bool OB>
__global__ __launch_bounds__(256) void softmax_kernel(const float* __restrict__ in,
                                                      void* __restrict__ outv) {
    int wave = threadIdx.x >> 6;
    int lane = threadIdx.x & 63;
    int row = blockIdx.x * 4 + wave;
    const float* p = in + (long)row * NC;
    constexpr int PER = NC / 64;
    float v[PER];
    float mx = -INFINITY;
#pragma unroll
    for (int j = 0; j < PER; ++j) { v[j] = p[lane + j * 64]; mx = fmaxf(mx, v[j]); }
#pragma unroll
    for (int off = 32; off; off >>= 1) mx = fmaxf(mx, __shfl_xor(mx, off));
    float sm = 0.f;
#pragma unroll
    for (int j = 0; j < PER; ++j) { v[j] = expf(v[j] - mx); sm += v[j]; }
#pragma unroll
    for (int off = 32; off; off >>= 1) sm += __shfl_xor(sm, off);
    float inv = 1.f / sm;
    if (OB) {
        short* o = (short*)outv + (long)row * NC;
#pragma unroll
        for (int j = 0; j < PER; ++j) o[lane + j * 64] = f2bf(v[j] * inv);
    } else {
        float* o = (float*)outv + (long)row * NC;
#pragma unroll
        for (int j = 0; j < PER; ++j) o[lane + j * 64] = v[j] * inv;
    }
}

// ---------------------------------------------------------------------------
// Pooled-adj normalization
// ---------------------------------------------------------------------------
template <int KC>
__global__ __launch_bounds__(256) void dinv_kernel(const float* __restrict__ adj,
                                                   float* __restrict__ dinv) {
    int wave = threadIdx.x >> 6;
    int lane = threadIdx.x & 63;
    int row = blockIdx.x * 4 + wave;
    int b = row / KC, r = row % KC;
    const float* p = adj + (long)b * KC * KC + (long)r * KC;
    float s = 0.f;
    for (int j = lane; j < KC; j += 64)
        if (j != r) s += p[j];
#pragma unroll
    for (int off = 32; off; off >>= 1) s += __shfl_xor(s, off);
    if (lane == 0) dinv[row] = 1.f / (sqrtf(s) + 1e-15f);
}

template <int KC>
__global__ __launch_bounds__(256) void scale_adj_kernel(float* __restrict__ adj,
                                                        const float* __restrict__ dinv) {
    long i = (long)blockIdx.x * 256 + threadIdx.x;
    int c = (int)(i % KC);
    long t = i / KC;
    int r = (int)(t % KC);
    int b = (int)(t / KC);
    float v = adj[i];
    v = (r == c) ? 0.f : v * dinv[b * KC + r] * dinv[b * KC + c];
    adj[i] = v;
}

// ---------------------------------------------------------------------------
// Readout
// ---------------------------------------------------------------------------
__global__ __launch_bounds__(128) void readout_kernel(const float* __restrict__ xd3,
                                                      const float* __restrict__ W_lin1,
                                                      const float* __restrict__ b_lin1,
                                                      const float* __restrict__ W_ro,
                                                      const float* __restrict__ b_ro,
                                                      float* __restrict__ out) {
    int b = blockIdx.x, t = threadIdx.x;
    __shared__ float g[128], g2[128], wred[2];
    const float* X = xd3 + (long)b * K2C * 128;
    float s = 0.f;
    for (int r = 0; r < K2C; ++r) s += X[r * 128 + t];
    g[t] = s * (1.f / (float)K2C);
    __syncthreads();
    float u = b_lin1[t];
    for (int k = 0; k < 128; ++k) u += g[k] * W_lin1[k * 128 + t];
    g2[t] = fmaxf(u, 0.f);
    __syncthreads();
    float p = g2[t] * W_ro[t];
#pragma unroll
    for (int off = 32; off; off >>= 1) p += __shfl_xor(p, off);
    if ((t & 63) == 0) wred[t >> 6] = p;
    __syncthreads();
    if (t == 0) {
        float tot = wred[0] + wred[1] + b_ro[0];
        out[b] = 1.f / (1.f + expf(-tot));
    }
}

// ---------------------------------------------------------------------------
extern "C" void kernel_launch(void* const* d_in, const int* in_sizes, int n_in,
                              void* d_out, int out_size, void* d_ws, size_t ws_size,
                              hipStream_t stream) {
    const float* x      = (const float*)d_in[0];
    const int*   ei     = (const int*)d_in[1];
    const float* eattr  = (const float*)d_in[2];
    const float* gamma  = (const float*)d_in[4];
    const float* beta   = (const float*)d_in[5];
    const float* Wq     = (const float*)d_in[6];
    const float* bq     = (const float*)d_in[7];
    const float* Wk     = (const float*)d_in[8];
    const float* bk     = (const float*)d_in[9];
    const float* Wv     = (const float*)d_in[10];
    const float* bv     = (const float*)d_in[11];
    const float* We     = (const float*)d_in[12];
    const float* Wskip  = (const float*)d_in[13];
    const float* bskip  = (const float*)d_in[14];
    const float* W_mlp1 = (const float*)d_in[15];
    const float* b_mlp1 = (const float*)d_in[16];
    const float* W2_rel = (const float*)d_in[17];
    const float* b2_rel = (const float*)d_in[18];
    const float* W2_root= (const float*)d_in[19];
    const float* W_mlp2 = (const float*)d_in[20];
    const float* b_mlp2 = (const float*)d_in[21];
    const float* W3_rel = (const float*)d_in[22];
    const float* b3_rel = (const float*)d_in[23];
    const float* W3_root= (const float*)d_in[24];
    const float* W_lin1 = (const float*)d_in[25];
    const float* b_lin1 = (const float*)d_in[26];
    const float* W_ro   = (const float*)d_in[27];
    const float* b_ro   = (const float*)d_in[28];
    float* out = (float*)d_out;

    char* w = (char*)d_ws;
    const size_t MB = 1ull << 20;
    // Workspace (peak 110 MB), lifetime-aliased (round-12 plan):
    short* qkvs = (short*)(w + 0);          // [NTOT,512] bf16 32MB
    float* s1f  = (float*)(w + 0);          // [NTOT,256] fp32 32MB
    short* S    = (short*)(w + 32 * MB);    // [NTOT,512] bf16 32MB
    short* h    = (short*)(w + 32 * MB);    // [NTOT,128] bf16 8MB (over dead S)
    short* T1s  = (short*)(w + 48 * MB);    // [NTOT,256] bf16 16MB
    short* s1b  = (short*)(w + 64 * MB);    // [NTOT,256] bf16 16MB
    unsigned char* Aden = (unsigned char*)(w + 80 * MB);  // [NTOT,512] u8 16MB
    float* tgc2 = (float*)(w + 48 * MB);    // [B,256,128] fp32 8MB
    short* xd2  = (short*)(w + 56 * MB);    // [B,256,128] bf16 4MB
    float* s2f  = (float*)(w + 64 * MB);    // [B,256,128] fp32 8MB
    short* s2b  = (short*)(w + 72 * MB);    // [B,256,128] bf16 4MB
    float* t2   = (float*)(w + 64 * MB);    // [B,256,128] fp32 8MB (over dead s2f)
    float* adj2 = (float*)(w + 0);          // [B,128,128] 4MB
    float* xp2  = (float*)(w + 4 * MB);     // [B,128,128] 4MB
    float* t3   = (float*)(w + 8 * MB);     // [B,128,128] 4MB
    float* xd3  = (float*)(w + 12 * MB);    // [B,128,128] 4MB
    float* adj1 = (float*)(w + 80 * MB);    // [B,256,256] 16MB (over dead Adense)
    float* xp1  = (float*)(w + 96 * MB);    // [B,256,128] 8MB
    float* ea5n = (float*)(w + 96 * MB);    // [NTOT,5] 640KB (dead before xp1)
    float* alpha= (float*)(w + 97 * MB);    // [EDGES] fp32 2MB (dead before xp1)
    float* linv = (float*)(w + 99 * MB);    // [NTOT] fp32 128KB (dead before xp1)
    char* misc  = w + 104 * MB;
    float* W4     = (float*)(misc + 0x00000);
    float* bias4  = (float*)(misc + 0x40000);
    float* scale  = (float*)(misc + 0x41400);
    float* shift  = (float*)(misc + 0x41600);
    float* dinv1  = (float*)(misc + 0x42000);
    float* dinv2  = (float*)(misc + 0x52000);
    int* deg_src  = (int*)(misc + 0x60000);
    int* deg_dst  = (int*)(misc + 0x80000);
    int* rp_src   = (int*)(misc + 0xA0000);
    int* rp_dst   = (int*)(misc + 0xC0000);
    int* cur_src  = (int*)(misc + 0xE0000);
    int* cur_dst  = (int*)(misc + 0x100000);
    int* eid_src  = (int*)(misc + 0x120000);
    int* eid_dst  = (int*)(misc + 0x320000);
    float* psum   = (float*)(misc + 0x520000);
    float* psq    = (float*)(misc + 0x540000);

    hipMemsetAsync(deg_src, 0, 2 * NTOT * sizeof(int), stream);

    // 1. BatchNorm affine params
    bn_stats_kernel<<<256, 256, 0, stream>>>(x, psum, psq);
    bn_finalize_kernel<<<1, 128, 0, stream>>>(psum, psq, gamma, beta, scale, shift);

    // 2. Pack fused qkvs weights
    pack_w4_kernel<<<256, 256, 0, stream>>>(Wq, Wk, Wv, Wskip, bq, bk, bv, bskip, W4, bias4);

    // 3. CSR by src and dst
    hist_kernel<<<EDGES / 256, 256, 0, stream>>>(ei, deg_src, deg_dst);
    scan2_kernel<<<2, 1024, 0, stream>>>(deg_src, rp_src, cur_src, deg_dst, rp_dst, cur_dst);
    scatter_kernel<<<EDGES / 256, 256, 0, stream>>>(ei, cur_src, cur_dst, eid_src, eid_dst);

    // 4. qkvs(bf16) = BN(x) @ [Wq|Wk|Wv|Wskip] + biases
    mgemm<128, false, true, false, false, true, false, false, false, false>
        <<<dim3(4, 256, 1), 256, 0, stream>>>(
        x, W4, nullptr, nullptr, 0, bias4, qkvs, scale, shift,
        NTOT, 512, 128, 128, 512, 512, 0, 0, 0);

    // 5. S(bf16) = (Q @ K^T) / sqrt(H) per graph (dense, MFMA)
    bgemm<true><<<dim3(4, 4, BGRAPH), 256, 0, stream>>>(
        qkvs + 0, qkvs + 128, S, 0.08838834764831845f,
        NNODE, NNODE, 128, 512, 512, 512,
        (long)NNODE * 512, (long)NNODE * 512, (long)NNODE * NNODE);

    // 6. Fused edge-softmax: raw alpha per edge-slot + linv + ea5n (no P matrix)
    attn_fuse_kernel<<<NTOT / 16, 256, 0, stream>>>(
        S, ei, eattr, We, rp_dst, deg_dst, eid_dst, qkvs, alpha, linv, ea5n);

    // 7. h(bf16) = relu(gatherPV + ea5n@We + skip) ; build Adense
    pv_gather_kernel<<<NTOT / 16, 256, 0, stream>>>(
        qkvs, ei, alpha, linv, rp_dst, deg_dst, eid_dst, ea5n, We, h);
    adense_kernel<<<NTOT / 16, 256, 0, stream>>>(ei, rp_src, deg_src, eid_src, Aden);

    // 8. s1f = h @ W_mlp1 + b ; s1b(bf16) = softmax(s1f)
    mgemm<128, false, false, false, false, false, false, false, false, true>
        <<<dim3(2, 256, 1), 256, 0, stream>>>(
        h, W_mlp1, nullptr, nullptr, 0, b_mlp1, s1f, nullptr, nullptr,
        NTOT, K1C, 128, 128, K1C, K1C, 0, 0, 0);
    softmax_kernel<K1C, true><<<NTOT / 4, 256, 0, stream>>>(s1f, s1b);

    // 9. T1(bf16) = Adense(u8) @ s1b(bf16) — 128-tile (deep K, 512 blocks)
    mgemm<128, false, false, false, false, true, true, true, false, false>
        <<<dim3(2, 4, BGRAPH), 256, 0, stream>>>(
        Aden, s1b, nullptr, nullptr, 0, nullptr, T1s, nullptr, nullptr,
        NNODE, K1C, NNODE, NNODE, K1C, K1C,
        (long)NNODE * NNODE, (long)NNODE * K1C, (long)NNODE * K1C);

    // 10. adj1 = s1b^T T1s — 128-tile ; xp1 = s1b^T h (64-tile)
    mgemm<128, true, false, false, false, false, false, true, true, false>
        <<<dim3(2, 2, BGRAPH), 256, 0, stream>>>(
        s1b, T1s, nullptr, nullptr, 0, nullptr, adj1, nullptr, nullptr,
        K1C, K1C, NNODE, K1C, K1C, K1C,
        (long)NNODE * K1C, (long)NNODE * K1C, (long)K1C * K1C);
    mgemm<64, true, false, false, false, false, false, true, true, false>
        <<<dim3(2, 4, BGRAPH), 256, 0, stream>>>(
        s1b, h, nullptr, nullptr, 0, nullptr, xp1, nullptr, nullptr,
        K1C, 128, NNODE, K1C, 128, 128,
        (long)NNODE * K1C, (long)NNODE * 128, (long)K1C * 128);

    // 11. Normalize adj1
    dinv_kernel<K1C><<<(BGRAPH * K1C) / 4, 256, 0, stream>>>(adj1, dinv1);
    scale_adj_kernel<K1C><<<(BGRAPH * K1C * K1C) / 256, 256, 0, stream>>>(adj1, dinv1);

    // 12. GraphConv2: tgc2 = adj1@xp1 ; xd2(bf16) = relu([tgc2|xp1]@[W2_rel;W2_root]+b)
    mgemm<64, false, false, false, false, false, false, false, false, false>
        <<<dim3(2, 4, BGRAPH), 256, 0, stream>>>(
        adj1, xp1, nullptr, nullptr, 0, nullptr, tgc2, nullptr, nullptr,
        K1C, 128, K1C, K1C, 128, 128,
        (long)K1C * K1C, (long)K1C * 128, (long)K1C * 128);
    mgemm<64, false, false, true, true, true, false, false, false, false>
        <<<dim3(2, 256, 1), 256, 0, stream>>>(
        tgc2, W2_rel, xp1, W2_root, 128, b2_rel, xd2, nullptr, nullptr,
        BGRAPH * K1C, 128, 256, 128, 128, 128, 0, 0, 0);

    // 13. s2f = xd2 @ W_mlp2 + b ; s2b(bf16) = softmax(s2f)
    mgemm<64, false, false, false, false, false, false, false, false, true>
        <<<dim3(2, 256, 1), 256, 0, stream>>>(
        xd2, W_mlp2, nullptr, nullptr, 0, b_mlp2, s2f, nullptr, nullptr,
        BGRAPH * K1C, K2C, 128, 128, K2C, K2C, 0, 0, 0);
    softmax_kernel<K2C, true><<<(BGRAPH * K1C) / 4, 256, 0, stream>>>(s2f, s2b);

    // 14. Pool2: t2 = adj1@s2b ; adj2 = s2b^T t2 ; xp2 = s2b^T xd2
    mgemm<64, false, false, false, false, false, false, true, false, false>
        <<<dim3(2, 4, BGRAPH), 256, 0, stream>>>(
        adj1, s2b, nullptr, nullptr, 0, nullptr, t2, nullptr, nullptr,
        K1C, K2C, K1C, K1C, K2C, K2C,
        (long)K1C * K1C, (long)K1C * K2C, (long)K1C * K2C);
    mgemm<64, true, false, false, false, false, false, false, true, false>
        <<<dim3(2, 2, BGRAPH), 256, 0, stream>>>(
        s2b, t2, nullptr, nullptr, 0, nullptr, adj2, nullptr, nullptr,
        K2C, K2C, K1C, K2C, K2C, K2C,
        (long)K1C * K2C, (long)K1C * K2C, (long)K2C * K2C);
    mgemm<64, true, false, false, false, false, false, true, true, false>
        <<<dim3(2, 2, BGRAPH), 256, 0, stream>>>(
        s2b, xd2, nullptr, nullptr, 0, nullptr, xp2, nullptr, nullptr,
        K2C, 128, K1C, K2C, 128, 128,
        (long)K1C * K2C, (long)K1C * 128, (long)K2C * 128);

    // 15. Normalize adj2
    dinv_kernel<K2C><<<(BGRAPH * K2C) / 4, 256, 0, stream>>>(adj2, dinv2);
    scale_adj_kernel<K2C><<<(BGRAPH * K2C * K2C) / 256, 256, 0, stream>>>(adj2, dinv2);

    // 16. GraphConv3: t3 = adj2@xp2 ; xd3 = [t3|xp2]@[W3_rel;W3_root] + b
    mgemm<64, false, false, false, false, false, false, false, false, false>
        <<<dim3(2, 2, BGRAPH), 256, 0, stream>>>(
        adj2, xp2, nullptr, nullptr, 0, nullptr, t3, nullptr, nullptr,
        K2C, 128, K2C, K2C, 128, 128,
        (long)K2C * K2C, (long)K2C * 128, (long)K2C * 128);
    mgemm<64, false, false, false, true, false, false, false, false, false>
        <<<dim3(2, 128, 1), 256, 0, stream>>>(
        t3, W3_rel, xp2, W3_root, 128, b3_rel, xd3, nullptr, nullptr,
        BGRAPH * K2C, 128, 256, 128, 128, 128, 0, 0, 0);

    // 17. Readout
    readout_kernel<<<BGRAPH, 128, 0, stream>>>(xd3, W_lin1, b_lin1, W_ro, b_ro, out);

    (void)in_sizes; (void)n_in; (void)out_size; (void)ws_size;
}

// Round 15
// 552.836 us; speedup vs baseline: 1.0149x; 1.0035x over previous
//
#include <hip/hip_runtime.h>
#include <math.h>

// Problem constants
#define BGRAPH 64
#define NNODE  512
#define NTOT   32768        // BGRAPH*NNODE
#define CIN    128
#define HDIM   128
#define EDIM_  5
#define EDGES  524288
#define K1C    256
#define K2C    128

using f32x4 = __attribute__((ext_vector_type(4))) float;
using s16x8 = __attribute__((ext_vector_type(8))) short;

__device__ __forceinline__ short f2bf(float f) {
    union { float f; unsigned u; } v; v.f = f;
    unsigned r = v.u + 0x7fffu + ((v.u >> 16) & 1u);   // RNE
    return (short)(r >> 16);
}
__device__ __forceinline__ float bf2f(short s) {
    union { unsigned u; float f; } v; v.u = ((unsigned)(unsigned short)s) << 16;
    return v.f;
}

// ---------------------------------------------------------------------------
// BatchNorm statistics: 256 blocks, float4 loads, per-block partials
// ---------------------------------------------------------------------------
__global__ __launch_bounds__(256) void bn_stats_kernel(const float* __restrict__ x,
                                                       float* __restrict__ psum,
                                                       float* __restrict__ psq) {
    int tid = threadIdx.x, bid = blockIdx.x;
    long idx0 = (long)bid * 256 + tid;
    float4 s = {0.f, 0.f, 0.f, 0.f}, q = {0.f, 0.f, 0.f, 0.f};
#pragma unroll
    for (int it = 0; it < 16; ++it) {
        float4 v = *(const float4*)(x + (idx0 + (long)it * 65536) * 4);
        s.x += v.x; s.y += v.y; s.z += v.z; s.w += v.w;
        q.x += v.x * v.x; q.y += v.y * v.y; q.z += v.z * v.z; q.w += v.w * v.w;
    }
    __shared__ float ss[128], sq[128];
    if (tid < 128) { ss[tid] = 0.f; sq[tid] = 0.f; }
    __syncthreads();
    int c0 = (tid & 31) * 4;
    atomicAdd(&ss[c0 + 0], s.x); atomicAdd(&ss[c0 + 1], s.y);
    atomicAdd(&ss[c0 + 2], s.z); atomicAdd(&ss[c0 + 3], s.w);
    atomicAdd(&sq[c0 + 0], q.x); atomicAdd(&sq[c0 + 1], q.y);
    atomicAdd(&sq[c0 + 2], q.z); atomicAdd(&sq[c0 + 3], q.w);
    __syncthreads();
    if (tid < 128) {
        psum[bid * 128 + tid] = ss[tid];
        psq[bid * 128 + tid]  = sq[tid];
    }
}

__global__ __launch_bounds__(128) void bn_finalize_kernel(const float* __restrict__ psum,
                                                          const float* __restrict__ psq,
                                                          const float* __restrict__ gamma,
                                                          const float* __restrict__ beta,
                                                          float* __restrict__ scale,
                                                          float* __restrict__ shift) {
    int c = threadIdx.x;
    float s = 0.f, q = 0.f;
    for (int b = 0; b < 256; ++b) { s += psum[b * 128 + c]; q += psq[b * 128 + c]; }
    float mu  = s / (float)NTOT;
    float var = q / (float)NTOT - mu * mu;
    float rstd = rsqrtf(var + 1e-5f);
    float sc = gamma[c] * rstd;
    scale[c] = sc;
    shift[c] = beta[c] - mu * sc;
}

// ---------------------------------------------------------------------------
// Pack Wq|Wk|Wv|Wskip into [128,512] and biases into [512]
// ---------------------------------------------------------------------------
__global__ __launch_bounds__(256) void pack_w4_kernel(const float* __restrict__ Wq, const float* __restrict__ Wk,
                                                      const float* __restrict__ Wv, const float* __restrict__ Ws,
                                                      const float* __restrict__ bq, const float* __restrict__ bk,
                                                      const float* __restrict__ bv, const float* __restrict__ bs,
                                                      float* __restrict__ W4, float* __restrict__ bias4) {
    int i = blockIdx.x * 256 + threadIdx.x;
    if (i < 128 * 512) {
        int k = i / 512, j = i % 512;
        float v;
        if (j < 128)      v = Wq[k * 128 + j];
        else if (j < 256) v = Wk[k * 128 + (j - 128)];
        else if (j < 384) v = Wv[k * 128 + (j - 256)];
        else              v = Ws[k * 128 + (j - 384)];
        W4[i] = v;
    }
    if (i < 512) {
        float v;
        if (i < 128)      v = bq[i];
        else if (i < 256) v = bk[i - 128];
        else if (i < 384) v = bv[i - 256];
        else              v = bs[i - 384];
        bias4[i] = v;
    }
}

// ---------------------------------------------------------------------------
// CSR build: histogram, scan (both arrays in one launch), scatter
// ---------------------------------------------------------------------------
__global__ __launch_bounds__(256) void hist_kernel(const int* __restrict__ ei,
                                                   int* __restrict__ deg_src,
                                                   int* __restrict__ deg_dst) {
    int e = blockIdx.x * 256 + threadIdx.x;
    if (e < EDGES) {
        atomicAdd(&deg_src[ei[e]], 1);
        atomicAdd(&deg_dst[ei[EDGES + e]], 1);
    }
}

__global__ __launch_bounds__(1024) void scan2_kernel(const int* __restrict__ deg_src,
                                                     int* __restrict__ rp_src, int* __restrict__ cur_src,
                                                     const int* __restrict__ deg_dst,
                                                     int* __restrict__ rp_dst, int* __restrict__ cur_dst) {
    const int* deg = blockIdx.x ? deg_dst : deg_src;
    int* rowptr    = blockIdx.x ? rp_dst  : rp_src;
    int* cursor    = blockIdx.x ? cur_dst : cur_src;
    __shared__ int part[1024];
    int tid = threadIdx.x;
    int base = tid * 32;
    int s = 0;
    for (int i = 0; i < 32; ++i) s += deg[base + i];
    part[tid] = s;
    __syncthreads();
    for (int off = 1; off < 1024; off <<= 1) {
        int v = part[tid];
        int add = (tid >= off) ? part[tid - off] : 0;
        __syncthreads();
        part[tid] = v + add;
        __syncthreads();
    }
    int run = (tid == 0) ? 0 : part[tid - 1];
    for (int i = 0; i < 32; ++i) {
        rowptr[base + i] = run;
        cursor[base + i] = run;
        run += deg[base + i];
    }
}

__global__ __launch_bounds__(256) void scatter_kernel(const int* __restrict__ ei,
                                                      int* __restrict__ cur_src, int* __restrict__ cur_dst,
                                                      int* __restrict__ eid_src, int* __restrict__ eid_dst) {
    int e = blockIdx.x * 256 + threadIdx.x;
    if (e < EDGES) {
        int s = ei[e], d = ei[EDGES + e];
        eid_src[atomicAdd(&cur_src[s], 1)] = e;
        eid_dst[atomicAdd(&cur_dst[d], 1)] = e;
    }
}

// ---------------------------------------------------------------------------
// BF16 MFMA GEMM, tile TILE x TILE (128 or 64), BK=32.
//   AU8: A uint8 counts. ATRBF16: TRANS_A bf16 A. ABF16: !TRANS_A bf16 A.
//   BBF16: B already bf16. OBF16: bf16 output. DUAL: concat-K second source.
// ---------------------------------------------------------------------------
template <int TILE, bool TRANS_A, bool AFFINE, bool RELU, bool DUAL,
          bool OBF16, bool AU8, bool BBF16, bool ATRBF16, bool ABF16>
__global__ __launch_bounds__(256) void mgemm(const void* __restrict__ Av,
                                             const void* __restrict__ Bv,
                                             const void* __restrict__ A2v,
                                             const void* __restrict__ B2v,
                                             int Ksplit,
                                             const float* __restrict__ bias,
                                             void* __restrict__ Cv,
                                             const float* __restrict__ scale,
                                             const float* __restrict__ shift,
                                             int M, int Nc, int K,
                                             int lda, int ldb, int ldc,
                                             long sA, long sB, long sC) {
    __shared__ __align__(16) short As[TILE * 40];
    __shared__ __align__(16) short Bs[TILE * 40];
    constexpr int ASZ = AU8 ? 1 : ((ATRBF16 || ABF16) ? 2 : 4);
    constexpr int BSZ = BBF16 ? 2 : 4;
    const char* Abase = (const char*)Av + (long)blockIdx.z * sA * ASZ;
    const char* Bbase = (const char*)Bv + (long)blockIdx.z * sB * BSZ;
    float* C = (float*)Cv + (OBF16 ? 0 : (long)blockIdx.z * sC);
    short* Cs = (short*)Cv + (OBF16 ? (long)blockIdx.z * sC : 0);
    const int m0 = blockIdx.y * TILE, n0 = blockIdx.x * TILE;
    const int tid = threadIdx.x;
    const int lane16 = tid & 15;
    const int quad = (tid & 63) >> 4;
    const int wrow = (tid >> 6) >> 1, wcol = (tid >> 6) & 1;
    constexpr int WT = TILE / 32;

    f32x4 acc[WT][WT] = {};

    for (int k0 = 0; k0 < K; k0 += 32) {
        const char* Au = Abase; const char* Bu = Bbase; int ku = k0;
        if (DUAL && k0 >= Ksplit) { Au = (const char*)A2v; Bu = (const char*)B2v; ku = k0 - Ksplit; }

        if (!TRANS_A) {
#pragma unroll
            for (int p = 0; p < TILE / 32; ++p) {
                int idx = tid + p * 256;
                int row = idx >> 3, c4 = idx & 7;
                short4 o;
                if (AU8) {
                    unsigned u = *(const unsigned*)((const unsigned char*)Au +
                                                    (long)(m0 + row) * lda + ku + c4 * 4);
                    o = make_short4(f2bf((float)(u & 255u)), f2bf((float)((u >> 8) & 255u)),
                                    f2bf((float)((u >> 16) & 255u)), f2bf((float)((u >> 24) & 255u)));
                } else if (ABF16) {
                    o = *(const short4*)((const short*)Au + (long)(m0 + row) * lda + ku + c4 * 4);
                } else {
                    float4 v = *(const float4*)((const float*)Au + (long)(m0 + row) * lda + ku + c4 * 4);
                    if (AFFINE) {
                        int k = ku + c4 * 4;
                        v.x = v.x * scale[k] + shift[k];
                        v.y = v.y * scale[k + 1] + shift[k + 1];
                        v.z = v.z * scale[k + 2] + shift[k + 2];
                        v.w = v.w * scale[k + 3] + shift[k + 3];
                    }
                    o = make_short4(f2bf(v.x), f2bf(v.y), f2bf(v.z), f2bf(v.w));
                }
                *(short4*)&As[row * 40 + c4 * 4] = o;
            }
        } else {
            if (TILE == 128 || tid < 128) {
                int c4 = tid >> 3, g = tid & 7;        // row-group slow, k-group fast
                short* d = &As[(c4 * 4) * 40 + g * 4];
                if (ATRBF16) {
                    const short* src = (const short*)Au + (long)(ku + g * 4) * lda + m0 + c4 * 4;
                    short4 r0 = *(const short4*)(src);
                    short4 r1 = *(const short4*)(src + lda);
                    short4 r2 = *(const short4*)(src + 2 * lda);
                    short4 r3 = *(const short4*)(src + 3 * lda);
                    *(short4*)(d + 0 * 40) = make_short4(r0.x, r1.x, r2.x, r3.x);
                    *(short4*)(d + 1 * 40) = make_short4(r0.y, r1.y, r2.y, r3.y);
                    *(short4*)(d + 2 * 40) = make_short4(r0.z, r1.z, r2.z, r3.z);
                    *(short4*)(d + 3 * 40) = make_short4(r0.w, r1.w, r2.w, r3.w);
                } else {
                    const float* src = (const float*)Au + (long)(ku + g * 4) * lda + m0 + c4 * 4;
                    float4 r0 = *(const float4*)(src);
                    float4 r1 = *(const float4*)(src + lda);
                    float4 r2 = *(const float4*)(src + 2 * lda);
                    float4 r3 = *(const float4*)(src + 3 * lda);
                    *(short4*)(d + 0 * 40) = make_short4(f2bf(r0.x), f2bf(r1.x), f2bf(r2.x), f2bf(r3.x));
                    *(short4*)(d + 1 * 40) = make_short4(f2bf(r0.y), f2bf(r1.y), f2bf(r2.y), f2bf(r3.y));
                    *(short4*)(d + 2 * 40) = make_short4(f2bf(r0.z), f2bf(r1.z), f2bf(r2.z), f2bf(r3.z));
                    *(short4*)(d + 3 * 40) = make_short4(f2bf(r0.w), f2bf(r1.w), f2bf(r2.w), f2bf(r3.w));
                }
            }
        }
        if (TILE == 128 || tid < 128) {
            int c4 = tid >> 3, g = tid & 7;            // n-group slow, k-group fast
            short* d = &Bs[(c4 * 4) * 40 + g * 4];
            if (BBF16) {
                const short* src = (const short*)Bu + (long)(ku + g * 4) * ldb + n0 + c4 * 4;
                short4 r0 = *(const short4*)(src);
                short4 r1 = *(const short4*)(src + ldb);
                short4 r2 = *(const short4*)(src + 2 * ldb);
                short4 r3 = *(const short4*)(src + 3 * ldb);
                *(short4*)(d + 0 * 40) = make_short4(r0.x, r1.x, r2.x, r3.x);
                *(short4*)(d + 1 * 40) = make_short4(r0.y, r1.y, r2.y, r3.y);
                *(short4*)(d + 2 * 40) = make_short4(r0.z, r1.z, r2.z, r3.z);
                *(short4*)(d + 3 * 40) = make_short4(r0.w, r1.w, r2.w, r3.w);
            } else {
                const float* src = (const float*)Bu + (long)(ku + g * 4) * ldb + n0 + c4 * 4;
                float4 r0 = *(const float4*)(src);
                float4 r1 = *(const float4*)(src + ldb);
                float4 r2 = *(const float4*)(src + 2 * ldb);
                float4 r3 = *(const float4*)(src + 3 * ldb);
                *(short4*)(d + 0 * 40) = make_short4(f2bf(r0.x), f2bf(r1.x), f2bf(r2.x), f2bf(r3.x));
                *(short4*)(d + 1 * 40) = make_short4(f2bf(r0.y), f2bf(r1.y), f2bf(r2.y), f2bf(r3.y));
                *(short4*)(d + 2 * 40) = make_short4(f2bf(r0.z), f2bf(r1.z), f2bf(r2.z), f2bf(r3.z));
                *(short4*)(d + 3 * 40) = make_short4(f2bf(r0.w), f2bf(r1.w), f2bf(r2.w), f2bf(r3.w));
            }
        }
        __syncthreads();

        s16x8 af[WT], bf[WT];
#pragma unroll
        for (int t = 0; t < WT; ++t) {
            af[t] = *(const s16x8*)&As[(wrow * (TILE / 2) + t * 16 + lane16) * 40 + quad * 8];
            bf[t] = *(const s16x8*)&Bs[(wcol * (TILE / 2) + t * 16 + lane16) * 40 + quad * 8];
        }
#pragma unroll
        for (int i = 0; i < WT; ++i)
#pragma unroll
            for (int j = 0; j < WT; ++j)
                acc[i][j] = __builtin_amdgcn_mfma_f32_16x16x32_bf16(af[i], bf[j], acc[i][j], 0, 0, 0);
        __syncthreads();
    }

#pragma unroll
    for (int i = 0; i < WT; ++i) {
        int gm = m0 + wrow * (TILE / 2) + i * 16 + quad * 4;
#pragma unroll
        for (int j = 0; j < WT; ++j) {
            int gn = n0 + wcol * (TILE / 2) + j * 16 + lane16;
            float bv = bias ? bias[gn] : 0.f;
#pragma unroll
            for (int r = 0; r < 4; ++r) {
                float val = acc[i][j][r] + bv;
                if (RELU) val = fmaxf(val, 0.f);
                if (OBF16) Cs[(long)(gm + r) * ldc + gn] = f2bf(val);
                else       C[(long)(gm + r) * ldc + gn] = val;
            }
        }
    }
}

// ---------------------------------------------------------------------------
// BF16-input MFMA GEMM (TRANS_B — used for QK^T): C = scale*(A@B^T)
// ---------------------------------------------------------------------------
template <bool OBF16>
__global__ __launch_bounds__(256) void bgemm(const short* __restrict__ A,
                                             const short* __restrict__ B,
                                             void* __restrict__ Cv,
                                             float outscale,
                                             int M, int Nc, int K,
                                             int lda, int ldb, int ldc,
                                             long sA, long sB, long sC) {
    __shared__ __align__(16) short As[128 * 40];
    __shared__ __align__(16) short Bs[128 * 40];
    const int z = blockIdx.z;
    A += (long)z * sA;
    B += (long)z * sB;
    float* C = (float*)Cv + (OBF16 ? 0 : (long)z * sC);
    short* Cs = (short*)Cv + (OBF16 ? (long)z * sC : 0);
    const int m0 = blockIdx.y * 128, n0 = blockIdx.x * 128;
    const int tid = threadIdx.x;
    const int lane16 = tid & 15;
    const int quad = (tid & 63) >> 4;
    const int wrow = (tid >> 6) >> 1, wcol = (tid >> 6) & 1;

    f32x4 acc[4][4] = {};

    for (int k0 = 0; k0 < K; k0 += 32) {
#pragma unroll
        for (int p = 0; p < 2; ++p) {
            int u = tid + p * 256;
            int row = u >> 2, g = u & 3;
            *(s16x8*)&As[row * 40 + g * 8] =
                *(const s16x8*)(A + (long)(m0 + row) * lda + k0 + g * 8);
        }
#pragma unroll
        for (int p = 0; p < 2; ++p) {
            int u = tid + p * 256;
            int row = u >> 2, g = u & 3;
            *(s16x8*)&Bs[row * 40 + g * 8] =
                *(const s16x8*)(B + (long)(n0 + row) * ldb + k0 + g * 8);
        }
        __syncthreads();

        s16x8 af[4], bf[4];
#pragma unroll
        for (int t = 0; t < 4; ++t) {
            af[t] = *(const s16x8*)&As[(wrow * 64 + t * 16 + lane16) * 40 + quad * 8];
            bf[t] = *(const s16x8*)&Bs[(wcol * 64 + t * 16 + lane16) * 40 + quad * 8];
        }
#pragma unroll
        for (int i = 0; i < 4; ++i)
#pragma unroll
            for (int j = 0; j < 4; ++j)
                acc[i][j] = __builtin_amdgcn_mfma_f32_16x16x32_bf16(af[i], bf[j], acc[i][j], 0, 0, 0);
        __syncthreads();
    }

#pragma unroll
    for (int i = 0; i < 4; ++i) {
        int gm = m0 + wrow * 64 + i * 16 + quad * 4;
#pragma unroll
        for (int j = 0; j < 4; ++j) {
            int gn = n0 + wcol * 64 + j * 16 + lane16;
#pragma unroll
            for (int r = 0; r < 4; ++r) {
                float val = acc[i][j][r] * outscale;
                if (OBF16) Cs[(long)(gm + r) * ldc + gn] = f2bf(val);
                else       C[(long)(gm + r) * ldc + gn] = val;
            }
        }
    }
}

// ---------------------------------------------------------------------------
// Fused edge-softmax from dense S (bf16): alpha[pos]=w raw, linv, ea5n.
// 16 lanes/dst node; inline qWe; no P matrix.
// ---------------------------------------------------------------------------
__global__ __launch_bounds__(256) void attn_fuse_kernel(const short* __restrict__ S,
                                                        const int* __restrict__ ei,
                                                        const float* __restrict__ eattr,
                                                        const float* __restrict__ We,
                                                        const int* __restrict__ rp_dst,
                                                        const int* __restrict__ deg_dst,
                                                        const int* __restrict__ eid_dst,
                                                        const short* __restrict__ qkvs,
                                                        float* __restrict__ alpha,
                                                        float* __restrict__ linv,
                                                        float* __restrict__ ea5n) {
    __shared__ float sWe[EDIM_ * 128];
    int g = threadIdx.x >> 4;
    int lane = threadIdx.x & 15;
    int node = blockIdx.x * 16 + g;
    for (int i = threadIdx.x; i < EDIM_ * 128; i += 256) sWe[i] = We[i];
    __syncthreads();

    // inline qWe: lane covers channels lane*8..+7, butterfly over 16 lanes
    float qw[EDIM_];
    {
        s16x8 qv = *(const s16x8*)(qkvs + (long)node * 512 + lane * 8);
        float qf[8];
#pragma unroll
        for (int j = 0; j < 8; ++j) qf[j] = bf2f(qv[j]);
#pragma unroll
        for (int d = 0; d < EDIM_; ++d) {
            float p = 0.f;
#pragma unroll
            for (int j = 0; j < 8; ++j) p += qf[j] * sWe[d * 128 + lane * 8 + j];
            qw[d] = p;
        }
#pragma unroll
        for (int off = 8; off; off >>= 1)
#pragma unroll
            for (int d = 0; d < EDIM_; ++d) qw[d] += __shfl_xor(qw[d], off);
#pragma unroll
        for (int d = 0; d < EDIM_; ++d) qw[d] *= 0.08838834764831845f;
    }

    int start = rp_dst[node], cnt = deg_dst[node];
    const short* Srow = S + (long)node * 512;
    float lsum = 0.f, a5[EDIM_] = {};
    for (int t = lane; t < cnt; t += 16) {
        int e = eid_dst[start + t];
        int src = ei[e] & 511;
        float lg = bf2f(Srow[src]);
        float ea[EDIM_];
#pragma unroll
        for (int d = 0; d < EDIM_; ++d) { ea[d] = eattr[e * EDIM_ + d]; lg += ea[d] * qw[d]; }
        float wv = expf(lg);                       // logits O(1): no max-pass needed
        alpha[start + t] = wv;
        lsum += wv;
#pragma unroll
        for (int d = 0; d < EDIM_; ++d) a5[d] += wv * ea[d];
    }
#pragma unroll
    for (int off = 8; off; off >>= 1) {
        lsum += __shfl_xor(lsum, off);
#pragma unroll
        for (int d = 0; d < EDIM_; ++d) a5[d] += __shfl_xor(a5[d], off);
    }
    float inv = (lsum > 0.f) ? 1.f / lsum : 0.f;
    if (lane == 0) linv[node] = inv;
    if (lane < EDIM_) {
        float v = lane == 0 ? a5[0] : lane == 1 ? a5[1] : lane == 2 ? a5[2]
                : lane == 3 ? a5[3] : a5[4];
        ea5n[node * EDIM_ + lane] = v * inv;
    }
}

// ---------------------------------------------------------------------------
// PV via edge gather: 16 lanes/dst node. Chunked index-prefetch + unrolled
// independent V loads; XCD swizzle for L2-resident V.
// ---------------------------------------------------------------------------
__global__ __launch_bounds__(256) void pv_gather_kernel(const short* __restrict__ qkvs,
                                                        const int* __restrict__ ei,
                                                        const float* __restrict__ alpha,
                                                        const float* __restrict__ linv,
                                                        const int* __restrict__ rp_dst,
                                                        const int* __restrict__ deg_dst,
                                                        const int* __restrict__ eid_dst,
                                                        const float* __restrict__ ea5n,
                                                        const float* __restrict__ We,
                                                        short* __restrict__ h) {
    __shared__ float sWe[EDIM_ * 128];
    for (int i = threadIdx.x; i < EDIM_ * 128; i += 256) sWe[i] = We[i];
    __syncthreads();
    int g = threadIdx.x >> 4;
    int lane = threadIdx.x & 15;
    int gbase = (threadIdx.x & 63) & ~15;
    int b = blockIdx.x;
    int xcd = b & 7, idx = b >> 3;
    int nb = (xcd * 8 + (idx >> 5)) * 32 + (idx & 31);
    int node = nb * 16 + g;
    int start = rp_dst[node], cnt = deg_dst[node];
    float acc[8] = {};
    for (int base = 0; base < cnt; base += 16) {
        int t = base + lane;
        int src = 0; float a = 0.f;
        if (t < cnt) {
            int e = eid_dst[start + t];
            src = ei[e];
            a = alpha[start + t];
        }
        int m = min(16, cnt - base);
        if (m == 16) {
#pragma unroll
            for (int j = 0; j < 16; ++j) {
                int   sj = __shfl(src, gbase + j);
                float aj = __shfl(a,   gbase + j);
                s16x8 v = *(const s16x8*)(qkvs + (long)sj * 512 + 256 + lane * 8);
#pragma unroll
                for (int k = 0; k < 8; ++k) acc[k] += aj * bf2f(v[k]);
            }
        } else {
            for (int j = 0; j < m; ++j) {
                int   sj = __shfl(src, gbase + j);
                float aj = __shfl(a,   gbase + j);
                s16x8 v = *(const s16x8*)(qkvs + (long)sj * 512 + 256 + lane * 8);
#pragma unroll
                for (int k = 0; k < 8; ++k) acc[k] += aj * bf2f(v[k]);
            }
        }
    }
    float inv = linv[node];
    float e5[EDIM_];
#pragma unroll
    for (int d = 0; d < EDIM_; ++d) e5[d] = ea5n[node * EDIM_ + d];
    s16x8 sk = *(const s16x8*)(qkvs + (long)node * 512 + 384 + lane * 8);
    s16x8 o;
#pragma unroll
    for (int j = 0; j < 8; ++j) {
        float ec = 0.f;
#pragma unroll
        for (int d = 0; d < EDIM_; ++d) ec += e5[d] * sWe[d * 128 + lane * 8 + j];
        float val = acc[j] * inv + ec + bf2f(sk[j]);
        o[j] = f2bf(fmaxf(val, 0.f));
    }
    *(s16x8*)(h + (long)node * 128 + lane * 8) = o;
}

// ---------------------------------------------------------------------------
// Dense adjacency count build (uint8 per (src,dst)), by src-CSR.
// ---------------------------------------------------------------------------
__global__ __launch_bounds__(256) void adense_kernel(const int* __restrict__ ei,
                                                     const int* __restrict__ rp_src,
                                                     const int* __restrict__ deg_src,
                                                     const int* __restrict__ eid_src,
                                                     unsigned char* __restrict__ Adense) {
    __shared__ int rows[16][512];
    int g = threadIdx.x >> 4;
    int lane = threadIdx.x & 15;
    int node = blockIdx.x * 16 + g;
    int* row = rows[g];
    for (int i = lane; i < 512; i += 16) row[i] = 0;
    int start = rp_src[node], cnt = deg_src[node];
    for (int t = lane; t < cnt; t += 16) {
        int e = eid_src[start + t];
        int dst = ei[EDGES + e] & 511;
        atomicAdd(&row[dst], 1);
    }
    unsigned* Ar = (unsigned*)(Adense + (long)node * 512);
    for (int i = lane; i < 128; i += 16) {
        unsigned p = (unsigned)row[4 * i]
                   | ((unsigned)row[4 * i + 1] << 8)
                   | ((unsigned)row[4 * i + 2] << 16)
                   | ((unsigned)row[4 * i + 3] << 24);
        Ar[i] = p;
    }
}

// ---------------------------------------------------------------------------
// Row-wise softmax; IB: bf16 input, OB: bf16 output
// ---------------------------------------------------------------------------
template <int NC, bool IB, bool OB>
__global__ __launch_bounds__(256) void softmax_kernel(const void* __restrict__ inv_,
                                                      void* __restrict__ outv) {
    int wave = threadIdx.x >> 6;
    int lane = threadIdx.x & 63;
    int row = blockIdx.x * 4 + wave;
    constexpr int PER = NC / 64;
    float v[PER];
    float mx = -INFINITY;
    if (IB) {
        const short* p = (const short*)inv_ + (long)row * NC;
#pragma unroll
        for (int j = 0; j < PER; ++j) { v[j] = bf2f(p[lane + j * 64]); mx = fmaxf(mx, v[j]); }
    } else {
        const float* p = (const float*)inv_ + (long)row * NC;
#pragma unroll
        for (int j = 0; j < PER; ++j) { v[j] = p[lane + j * 64]; mx = fmaxf(mx, v[j]); }
    }
#pragma unroll
    for (int off = 32; off; off >>= 1) mx = fmaxf(mx, __shfl_xor(mx, off));
    float sm = 0.f;
#pragma unroll
    for (int j = 0; j < PER; ++j) { v[j] = expf(v[j] - mx); sm += v[j]; }
#pragma unroll
    for (int off = 32; off; off >>= 1) sm += __shfl_xor(sm, off);
    float inv = 1.f / sm;
    if (OB) {
        short* o = (short*)outv + (long)row * NC;
#pragma unroll
        for (int j = 0; j < PER; ++j) o[lane + j * 64] = f2bf(v[j] * inv);
    } else {
        float* o = (float*)outv + (long)row * NC;
#pragma unroll
        for (int j = 0; j < PER; ++j) o[lane + j * 64] = v[j] * inv;
    }
}

// ---------------------------------------------------------------------------
// Pooled-adj normalization
// ---------------------------------------------------------------------------
template <int KC>
__global__ __launch_bounds__(256) void dinv_kernel(const float* __restrict__ adj,
                                                   float* __restrict__ dinv) {
    int wave = threadIdx.x >> 6;
    int lane = threadIdx.x & 63;
    int row = blockIdx.x * 4 + wave;
    int b = row / KC, r = row % KC;
    const float* p = adj + (long)b * KC * KC + (long)r * KC;
    float s = 0.f;
    for (int j = lane; j < KC; j += 64)
        if (j != r) s += p[j];
#pragma unroll
    for (int off = 32; off; off >>= 1) s += __shfl_xor(s, off);
    if (lane == 0) dinv[row] = 1.f / (sqrtf(s) + 1e-15f);
}

template <int KC>
__global__ __launch_bounds__(256) void scale_adj_kernel(float* __restrict__ adj,
                                                        const float* __restrict__ dinv) {
    long i = (long)blockIdx.x * 256 + threadIdx.x;
    int c = (int)(i % KC);
    long t = i / KC;
    int r = (int)(t % KC);
    int b = (int)(t / KC);
    float v = adj[i];
    v = (r == c) ? 0.f : v * dinv[b * KC + r] * dinv[b * KC + c];
    adj[i] = v;
}

// ---------------------------------------------------------------------------
// Readout
// ---------------------------------------------------------------------------
__global__ __launch_bounds__(128) void readout_kernel(const float* __restrict__ xd3,
                                                      const float* __restrict__ W_lin1,
                                                      const float* __restrict__ b_lin1,
                                                      const float* __restrict__ W_ro,
                                                      const float* __restrict__ b_ro,
                                                      float* __restrict__ out) {
    int b = blockIdx.x, t = threadIdx.x;
    __shared__ float g[128], g2[128], wred[2];
    const float* X = xd3 + (long)b * K2C * 128;
    float s = 0.f;
    for (int r = 0; r < K2C; ++r) s += X[r * 128 + t];
    g[t] = s * (1.f / (float)K2C);
    __syncthreads();
    float u = b_lin1[t];
    for (int k = 0; k < 128; ++k) u += g[k] * W_lin1[k * 128 + t];
    g2[t] = fmaxf(u, 0.f);
    __syncthreads();
    float p = g2[t] * W_ro[t];
#pragma unroll
    for (int off = 32; off; off >>= 1) p += __shfl_xor(p, off);
    if ((t & 63) == 0) wred[t >> 6] = p;
    __syncthreads();
    if (t == 0) {
        float tot = wred[0] + wred[1] + b_ro[0];
        out[b] = 1.f / (1.f + expf(-tot));
    }
}

// ---------------------------------------------------------------------------
extern "C" void kernel_launch(void* const* d_in, const int* in_sizes, int n_in,
                              void* d_out, int out_size, void* d_ws, size_t ws_size,
                              hipStream_t stream) {
    const float* x      = (const float*)d_in[0];
    const int*   ei     = (const int*)d_in[1];
    const float* eattr  = (const float*)d_in[2];
    const float* gamma  = (const float*)d_in[4];
    const float* beta   = (const float*)d_in[5];
    const float* Wq     = (const float*)d_in[6];
    const float* bq     = (const float*)d_in[7];
    const float* Wk     = (const float*)d_in[8];
    const float* bk     = (const float*)d_in[9];
    const float* Wv     = (const float*)d_in[10];
    const float* bv     = (const float*)d_in[11];
    const float* We     = (const float*)d_in[12];
    const float* Wskip  = (const float*)d_in[13];
    const float* bskip  = (const float*)d_in[14];
    const float* W_mlp1 = (const float*)d_in[15];
    const float* b_mlp1 = (const float*)d_in[16];
    const float* W2_rel = (const float*)d_in[17];
    const float* b2_rel = (const float*)d_in[18];
    const float* W2_root= (const float*)d_in[19];
    const float* W_mlp2 = (const float*)d_in[20];
    const float* b_mlp2 = (const float*)d_in[21];
    const float* W3_rel = (const float*)d_in[22];
    const float* b3_rel = (const float*)d_in[23];
    const float* W3_root= (const float*)d_in[24];
    const float* W_lin1 = (const float*)d_in[25];
    const float* b_lin1 = (const float*)d_in[26];
    const float* W_ro   = (const float*)d_in[27];
    const float* b_ro   = (const float*)d_in[28];
    float* out = (float*)d_out;

    char* w = (char*)d_ws;
    const size_t MB = 1ull << 20;
    // Workspace (peak 110 MB), lifetime-aliased (round-12 plan; s1f/s2f now bf16):
    short* qkvs = (short*)(w + 0);          // [NTOT,512] bf16 32MB (dead after step 7)
    short* s1fb = (short*)(w + 0);          // [NTOT,256] bf16 16MB (step 8, over dead qkvs)
    short* S    = (short*)(w + 32 * MB);    // [NTOT,512] bf16 32MB
    short* h    = (short*)(w + 32 * MB);    // [NTOT,128] bf16 8MB (over dead S)
    short* T1s  = (short*)(w + 48 * MB);    // [NTOT,256] bf16 16MB
    short* s1b  = (short*)(w + 64 * MB);    // [NTOT,256] bf16 16MB
    unsigned char* Aden = (unsigned char*)(w + 80 * MB);  // [NTOT,512] u8 16MB
    float* tgc2 = (float*)(w + 48 * MB);    // [B,256,128] fp32 8MB
    short* xd2  = (short*)(w + 56 * MB);    // [B,256,128] bf16 4MB
    short* s2fb = (short*)(w + 64 * MB);    // [B,256,128] bf16 4MB
    short* s2b  = (short*)(w + 72 * MB);    // [B,256,128] bf16 4MB
    float* t2   = (float*)(w + 64 * MB);    // [B,256,128] fp32 8MB (over dead s2fb)
    float* adj2 = (float*)(w + 0);          // [B,128,128] 4MB
    float* xp2  = (float*)(w + 4 * MB);     // [B,128,128] 4MB
    float* t3   = (float*)(w + 8 * MB);     // [B,128,128] 4MB
    float* xd3  = (float*)(w + 12 * MB);    // [B,128,128] 4MB
    float* adj1 = (float*)(w + 80 * MB);    // [B,256,256] 16MB (over dead Adense)
    float* xp1  = (float*)(w + 96 * MB);    // [B,256,128] 8MB
    float* ea5n = (float*)(w + 96 * MB);    // [NTOT,5] 640KB (dead before xp1)
    float* alpha= (float*)(w + 97 * MB);    // [EDGES] fp32 2MB (dead before xp1)
    float* linv = (float*)(w + 99 * MB);    // [NTOT] fp32 128KB (dead before xp1)
    char* misc  = w + 104 * MB;
    float* W4     = (float*)(misc + 0x00000);
    float* bias4  = (float*)(misc + 0x40000);
    float* scale  = (float*)(misc + 0x41400);
    float* shift  = (float*)(misc + 0x41600);
    float* dinv1  = (float*)(misc + 0x42000);
    float* dinv2  = (float*)(misc + 0x52000);
    int* deg_src  = (int*)(misc + 0x60000);
    int* deg_dst  = (int*)(misc + 0x80000);
    int* rp_src   = (int*)(misc + 0xA0000);
    int* rp_dst   = (int*)(misc + 0xC0000);
    int* cur_src  = (int*)(misc + 0xE0000);
    int* cur_dst  = (int*)(misc + 0x100000);
    int* eid_src  = (int*)(misc + 0x120000);
    int* eid_dst  = (int*)(misc + 0x320000);
    float* psum   = (float*)(misc + 0x520000);
    float* psq    = (float*)(misc + 0x540000);

    hipMemsetAsync(deg_src, 0, 2 * NTOT * sizeof(int), stream);

    // 1. BatchNorm affine params
    bn_stats_kernel<<<256, 256, 0, stream>>>(x, psum, psq);
    bn_finalize_kernel<<<1, 128, 0, stream>>>(psum, psq, gamma, beta, scale, shift);

    // 2. Pack fused qkvs weights
    pack_w4_kernel<<<256, 256, 0, stream>>>(Wq, Wk, Wv, Wskip, bq, bk, bv, bskip, W4, bias4);

    // 3. CSR by src and dst
    hist_kernel<<<EDGES / 256, 256, 0, stream>>>(ei, deg_src, deg_dst);
    scan2_kernel<<<2, 1024, 0, stream>>>(deg_src, rp_src, cur_src, deg_dst, rp_dst, cur_dst);
    scatter_kernel<<<EDGES / 256, 256, 0, stream>>>(ei, cur_src, cur_dst, eid_src, eid_dst);

    // 4. qkvs(bf16) = BN(x) @ [Wq|Wk|Wv|Wskip] + biases
    mgemm<128, false, true, false, false, true, false, false, false, false>
        <<<dim3(4, 256, 1), 256, 0, stream>>>(
        x, W4, nullptr, nullptr, 0, bias4, qkvs, scale, shift,
        NTOT, 512, 128, 128, 512, 512, 0, 0, 0);

    // 5. S(bf16) = (Q @ K^T) / sqrt(H) per graph (dense, MFMA)
    bgemm<true><<<dim3(4, 4, BGRAPH), 256, 0, stream>>>(
        qkvs + 0, qkvs + 128, S, 0.08838834764831845f,
        NNODE, NNODE, 128, 512, 512, 512,
        (long)NNODE * 512, (long)NNODE * 512, (long)NNODE * NNODE);

    // 6. Fused edge-softmax: raw alpha per edge-slot + linv + ea5n
    attn_fuse_kernel<<<NTOT / 16, 256, 0, stream>>>(
        S, ei, eattr, We, rp_dst, deg_dst, eid_dst, qkvs, alpha, linv, ea5n);

    // 7. h(bf16) = relu(gatherPV + ea5n@We + skip) ; build Adense
    pv_gather_kernel<<<NTOT / 16, 256, 0, stream>>>(
        qkvs, ei, alpha, linv, rp_dst, deg_dst, eid_dst, ea5n, We, h);
    adense_kernel<<<NTOT / 16, 256, 0, stream>>>(ei, rp_src, deg_src, eid_src, Aden);

    // 8. s1fb(bf16) = h @ W_mlp1 + b ; s1b(bf16) = softmax(s1fb)
    mgemm<128, false, false, false, false, true, false, false, false, true>
        <<<dim3(2, 256, 1), 256, 0, stream>>>(
        h, W_mlp1, nullptr, nullptr, 0, b_mlp1, s1fb, nullptr, nullptr,
        NTOT, K1C, 128, 128, K1C, K1C, 0, 0, 0);
    softmax_kernel<K1C, true, true><<<NTOT / 4, 256, 0, stream>>>(s1fb, s1b);

    // 9. T1(bf16) = Adense(u8) @ s1b(bf16) — 128-tile (deep K, 512 blocks)
    mgemm<128, false, false, false, false, true, true, true, false, false>
        <<<dim3(2, 4, BGRAPH), 256, 0, stream>>>(
        Aden, s1b, nullptr, nullptr, 0, nullptr, T1s, nullptr, nullptr,
        NNODE, K1C, NNODE, NNODE, K1C, K1C,
        (long)NNODE * NNODE, (long)NNODE * K1C, (long)NNODE * K1C);

    // 10. adj1 = s1b^T T1s — 128-tile ; xp1 = s1b^T h (64-tile)
    mgemm<128, true, false, false, false, false, false, true, true, false>
        <<<dim3(2, 2, BGRAPH), 256, 0, stream>>>(
        s1b, T1s, nullptr, nullptr, 0, nullptr, adj1, nullptr, nullptr,
        K1C, K1C, NNODE, K1C, K1C, K1C,
        (long)NNODE * K1C, (long)NNODE * K1C, (long)K1C * K1C);
    mgemm<64, true, false, false, false, false, false, true, true, false>
        <<<dim3(2, 4, BGRAPH), 256, 0, stream>>>(
        s1b, h, nullptr, nullptr, 0, nullptr, xp1, nullptr, nullptr,
        K1C, 128, NNODE, K1C, 128, 128,
        (long)NNODE * K1C, (long)NNODE * 128, (long)K1C * 128);

    // 11. Normalize adj1
    dinv_kernel<K1C><<<(BGRAPH * K1C) / 4, 256, 0, stream>>>(adj1, dinv1);
    scale_adj_kernel<K1C><<<(BGRAPH * K1C * K1C) / 256, 256, 0, stream>>>(adj1, dinv1);

    // 12. GraphConv2: tgc2 = adj1@xp1 ; xd2(bf16) = relu([tgc2|xp1]@[W2_rel;W2_root]+b)
    mgemm<64, false, false, false, false, false, false, false, false, false>
        <<<dim3(2, 4, BGRAPH), 256, 0, stream>>>(
        adj1, xp1, nullptr, nullptr, 0, nullptr, tgc2, nullptr, nullptr,
        K1C, 128, K1C, K1C, 128, 128,
        (long)K1C * K1C, (long)K1C * 128, (long)K1C * 128);
    mgemm<64, false, false, true, true, true, false, false, false, false>
        <<<dim3(2, 256, 1), 256, 0, stream>>>(
        tgc2, W2_rel, xp1, W2_root, 128, b2_rel, xd2, nullptr, nullptr,
        BGRAPH * K1C, 128, 256, 128, 128, 128, 0, 0, 0);

    // 13. s2fb(bf16) = xd2 @ W_mlp2 + b ; s2b(bf16) = softmax(s2fb)
    mgemm<64, false, false, false, false, true, false, false, false, true>
        <<<dim3(2, 256, 1), 256, 0, stream>>>(
        xd2, W_mlp2, nullptr, nullptr, 0, b_mlp2, s2fb, nullptr, nullptr,
        BGRAPH * K1C, K2C, 128, 128, K2C, K2C, 0, 0, 0);
    softmax_kernel<K2C, true, true><<<(BGRAPH * K1C) / 4, 256, 0, stream>>>(s2fb, s2b);

    // 14. Pool2: t2 = adj1@s2b ; adj2 = s2b^T t2 ; xp2 = s2b^T xd2
    mgemm<64, false, false, false, false, false, false, true, false, false>
        <<<dim3(2, 4, BGRAPH), 256, 0, stream>>>(
        adj1, s2b, nullptr, nullptr, 0, nullptr, t2, nullptr, nullptr,
        K1C, K2C, K1C, K1C, K2C, K2C,
        (long)K1C * K1C, (long)K1C * K2C, (long)K1C * K2C);
    mgemm<64, true, false, false, false, false, false, false, true, false>
        <<<dim3(2, 2, BGRAPH), 256, 0, stream>>>(
        s2b, t2, nullptr, nullptr, 0, nullptr, adj2, nullptr, nullptr,
        K2C, K2C, K1C, K2C, K2C, K2C,
        (long)K1C * K2C, (long)K1C * K2C, (long)K2C * K2C);
    mgemm<64, true, false, false, false, false, false, true, true, false>
        <<<dim3(2, 2, BGRAPH), 256, 0, stream>>>(
        s2b, xd2, nullptr, nullptr, 0, nullptr, xp2, nullptr, nullptr,
        K2C, 128, K1C, K2C, 128, 128,
        (long)K1C * K2C, (long)K1C * 128, (long)K2C * 128);

    // 15. Normalize adj2
    dinv_kernel<K2C><<<(BGRAPH * K2C) / 4, 256, 0, stream>>>(adj2, dinv2);
    scale_adj_kernel<K2C><<<(BGRAPH * K2C * K2C) / 256, 256, 0, stream>>>(adj2, dinv2);

    // 16. GraphConv3: t3 = adj2@xp2 ; xd3 = [t3|xp2]@[W3_rel;W3_root] + b
    mgemm<64, false, false, false, false, false, false, false, false, false>
        <<<dim3(2, 2, BGRAPH), 256, 0, stream>>>(
        adj2, xp2, nullptr, nullptr, 0, nullptr, t3, nullptr, nullptr,
        K2C, 128, K2C, K2C, 128, 128,
        (long)K2C * K2C, (long)K2C * 128, (long)K2C * 128);
    mgemm<64, false, false, false, true, false, false, false, false, false>
        <<<dim3(2, 128, 1), 256, 0, stream>>>(
        t3, W3_rel, xp2, W3_root, 128, b3_rel, xd3, nullptr, nullptr,
        BGRAPH * K2C, 128, 256, 128, 128, 128, 0, 0, 0);

    // 17. Readout
    readout_kernel<<<BGRAPH, 128, 0, stream>>>(xd3, W_lin1, b_lin1, W_ro, b_ro, out);

    (void)in_sizes; (void)n_in; (void)out_size; (void)ws_size;
}

// Round 16
// 536.169 us; speedup vs baseline: 1.0465x; 1.0311x over previous
//
#include <hip/hip_runtime.h>
#include <math.h>

// Problem constants
#define BGRAPH 64
#define NNODE  512
#define NTOT   32768        // BGRAPH*NNODE
#define CIN    128
#define HDIM   128
#define EDIM_  5
#define EDGES  524288
#define K1C    256
#define K2C    128

using f32x4 = __attribute__((ext_vector_type(4))) float;
using s16x8 = __attribute__((ext_vector_type(8))) short;

__device__ __forceinline__ short f2bf(float f) {
    union { float f; unsigned u; } v; v.f = f;
    unsigned r = v.u + 0x7fffu + ((v.u >> 16) & 1u);   // RNE
    return (short)(r >> 16);
}
__device__ __forceinline__ float bf2f(short s) {
    union { unsigned u; float f; } v; v.u = ((unsigned)(unsigned short)s) << 16;
    return v.f;
}

// ---------------------------------------------------------------------------
// BatchNorm statistics: 256 blocks, float4 loads, per-block partials
// ---------------------------------------------------------------------------
__global__ __launch_bounds__(256) void bn_stats_kernel(const float* __restrict__ x,
                                                       float* __restrict__ psum,
                                                       float* __restrict__ psq) {
    int tid = threadIdx.x, bid = blockIdx.x;
    long idx0 = (long)bid * 256 + tid;
    float4 s = {0.f, 0.f, 0.f, 0.f}, q = {0.f, 0.f, 0.f, 0.f};
#pragma unroll
    for (int it = 0; it < 16; ++it) {
        float4 v = *(const float4*)(x + (idx0 + (long)it * 65536) * 4);
        s.x += v.x; s.y += v.y; s.z += v.z; s.w += v.w;
        q.x += v.x * v.x; q.y += v.y * v.y; q.z += v.z * v.z; q.w += v.w * v.w;
    }
    __shared__ float ss[128], sq[128];
    if (tid < 128) { ss[tid] = 0.f; sq[tid] = 0.f; }
    __syncthreads();
    int c0 = (tid & 31) * 4;
    atomicAdd(&ss[c0 + 0], s.x); atomicAdd(&ss[c0 + 1], s.y);
    atomicAdd(&ss[c0 + 2], s.z); atomicAdd(&ss[c0 + 3], s.w);
    atomicAdd(&sq[c0 + 0], q.x); atomicAdd(&sq[c0 + 1], q.y);
    atomicAdd(&sq[c0 + 2], q.z); atomicAdd(&sq[c0 + 3], q.w);
    __syncthreads();
    if (tid < 128) {
        psum[bid * 128 + tid] = ss[tid];
        psq[bid * 128 + tid]  = sq[tid];
    }
}

__global__ __launch_bounds__(128) void bn_finalize_kernel(const float* __restrict__ psum,
                                                          const float* __restrict__ psq,
                                                          const float* __restrict__ gamma,
                                                          const float* __restrict__ beta,
                                                          float* __restrict__ scale,
                                                          float* __restrict__ shift) {
    int c = threadIdx.x;
    float s = 0.f, q = 0.f;
    for (int b = 0; b < 256; ++b) { s += psum[b * 128 + c]; q += psq[b * 128 + c]; }
    float mu  = s / (float)NTOT;
    float var = q / (float)NTOT - mu * mu;
    float rstd = rsqrtf(var + 1e-5f);
    float sc = gamma[c] * rstd;
    scale[c] = sc;
    shift[c] = beta[c] - mu * sc;
}

// ---------------------------------------------------------------------------
// Pack Wq|Wk|Wv|Wskip into [128,512] and biases into [512]
// ---------------------------------------------------------------------------
__global__ __launch_bounds__(256) void pack_w4_kernel(const float* __restrict__ Wq, const float* __restrict__ Wk,
                                                      const float* __restrict__ Wv, const float* __restrict__ Ws,
                                                      const float* __restrict__ bq, const float* __restrict__ bk,
                                                      const float* __restrict__ bv, const float* __restrict__ bs,
                                                      float* __restrict__ W4, float* __restrict__ bias4) {
    int i = blockIdx.x * 256 + threadIdx.x;
    if (i < 128 * 512) {
        int k = i / 512, j = i % 512;
        float v;
        if (j < 128)      v = Wq[k * 128 + j];
        else if (j < 256) v = Wk[k * 128 + (j - 128)];
        else if (j < 384) v = Wv[k * 128 + (j - 256)];
        else              v = Ws[k * 128 + (j - 384)];
        W4[i] = v;
    }
    if (i < 512) {
        float v;
        if (i < 128)      v = bq[i];
        else if (i < 256) v = bk[i - 128];
        else if (i < 384) v = bv[i - 256];
        else              v = bs[i - 384];
        bias4[i] = v;
    }
}

// ---------------------------------------------------------------------------
// CSR build: histogram, scan (both arrays in one launch), scatter
// ---------------------------------------------------------------------------
__global__ __launch_bounds__(256) void hist_kernel(const int* __restrict__ ei,
                                                   int* __restrict__ deg_src,
                                                   int* __restrict__ deg_dst) {
    int e = blockIdx.x * 256 + threadIdx.x;
    if (e < EDGES) {
        atomicAdd(&deg_src[ei[e]], 1);
        atomicAdd(&deg_dst[ei[EDGES + e]], 1);
    }
}

__global__ __launch_bounds__(1024) void scan2_kernel(const int* __restrict__ deg_src,
                                                     int* __restrict__ rp_src, int* __restrict__ cur_src,
                                                     const int* __restrict__ deg_dst,
                                                     int* __restrict__ rp_dst, int* __restrict__ cur_dst) {
    const int* deg = blockIdx.x ? deg_dst : deg_src;
    int* rowptr    = blockIdx.x ? rp_dst  : rp_src;
    int* cursor    = blockIdx.x ? cur_dst : cur_src;
    __shared__ int part[1024];
    int tid = threadIdx.x;
    int base = tid * 32;
    int s = 0;
    for (int i = 0; i < 32; ++i) s += deg[base + i];
    part[tid] = s;
    __syncthreads();
    for (int off = 1; off < 1024; off <<= 1) {
        int v = part[tid];
        int add = (tid >= off) ? part[tid - off] : 0;
        __syncthreads();
        part[tid] = v + add;
        __syncthreads();
    }
    int run = (tid == 0) ? 0 : part[tid - 1];
    for (int i = 0; i < 32; ++i) {
        rowptr[base + i] = run;
        cursor[base + i] = run;
        run += deg[base + i];
    }
}

__global__ __launch_bounds__(256) void scatter_kernel(const int* __restrict__ ei,
                                                      int* __restrict__ cur_src, int* __restrict__ cur_dst,
                                                      int* __restrict__ eid_src, int* __restrict__ eid_dst) {
    int e = blockIdx.x * 256 + threadIdx.x;
    if (e < EDGES) {
        int s = ei[e], d = ei[EDGES + e];
        eid_src[atomicAdd(&cur_src[s], 1)] = e;
        eid_dst[atomicAdd(&cur_dst[d], 1)] = e;
    }
}

// ---------------------------------------------------------------------------
// BF16 MFMA GEMM, tile TILE x TILE (128 or 64), BK=32.
//   AU8: A uint8 counts. ATRBF16: TRANS_A bf16 A. ABF16: !TRANS_A bf16 A.
//   BBF16: B already bf16. OBF16: bf16 output. DUAL: concat-K second source.
// ---------------------------------------------------------------------------
template <int TILE, bool TRANS_A, bool AFFINE, bool RELU, bool DUAL,
          bool OBF16, bool AU8, bool BBF16, bool ATRBF16, bool ABF16>
__global__ __launch_bounds__(256) void mgemm(const void* __restrict__ Av,
                                             const void* __restrict__ Bv,
                                             const void* __restrict__ A2v,
                                             const void* __restrict__ B2v,
                                             int Ksplit,
                                             const float* __restrict__ bias,
                                             void* __restrict__ Cv,
                                             const float* __restrict__ scale,
                                             const float* __restrict__ shift,
                                             int M, int Nc, int K,
                                             int lda, int ldb, int ldc,
                                             long sA, long sB, long sC) {
    __shared__ __align__(16) short As[TILE * 40];
    __shared__ __align__(16) short Bs[TILE * 40];
    constexpr int ASZ = AU8 ? 1 : ((ATRBF16 || ABF16) ? 2 : 4);
    constexpr int BSZ = BBF16 ? 2 : 4;
    const char* Abase = (const char*)Av + (long)blockIdx.z * sA * ASZ;
    const char* Bbase = (const char*)Bv + (long)blockIdx.z * sB * BSZ;
    float* C = (float*)Cv + (OBF16 ? 0 : (long)blockIdx.z * sC);
    short* Cs = (short*)Cv + (OBF16 ? (long)blockIdx.z * sC : 0);
    const int m0 = blockIdx.y * TILE, n0 = blockIdx.x * TILE;
    const int tid = threadIdx.x;
    const int lane16 = tid & 15;
    const int quad = (tid & 63) >> 4;
    const int wrow = (tid >> 6) >> 1, wcol = (tid >> 6) & 1;
    constexpr int WT = TILE / 32;

    f32x4 acc[WT][WT] = {};

    for (int k0 = 0; k0 < K; k0 += 32) {
        const char* Au = Abase; const char* Bu = Bbase; int ku = k0;
        if (DUAL && k0 >= Ksplit) { Au = (const char*)A2v; Bu = (const char*)B2v; ku = k0 - Ksplit; }

        if (!TRANS_A) {
#pragma unroll
            for (int p = 0; p < TILE / 32; ++p) {
                int idx = tid + p * 256;
                int row = idx >> 3, c4 = idx & 7;
                short4 o;
                if (AU8) {
                    unsigned u = *(const unsigned*)((const unsigned char*)Au +
                                                    (long)(m0 + row) * lda + ku + c4 * 4);
                    o = make_short4(f2bf((float)(u & 255u)), f2bf((float)((u >> 8) & 255u)),
                                    f2bf((float)((u >> 16) & 255u)), f2bf((float)((u >> 24) & 255u)));
                } else if (ABF16) {
                    o = *(const short4*)((const short*)Au + (long)(m0 + row) * lda + ku + c4 * 4);
                } else {
                    float4 v = *(const float4*)((const float*)Au + (long)(m0 + row) * lda + ku + c4 * 4);
                    if (AFFINE) {
                        int k = ku + c4 * 4;
                        v.x = v.x * scale[k] + shift[k];
                        v.y = v.y * scale[k + 1] + shift[k + 1];
                        v.z = v.z * scale[k + 2] + shift[k + 2];
                        v.w = v.w * scale[k + 3] + shift[k + 3];
                    }
                    o = make_short4(f2bf(v.x), f2bf(v.y), f2bf(v.z), f2bf(v.w));
                }
                *(short4*)&As[row * 40 + c4 * 4] = o;
            }
        } else {
            if (TILE == 128 || tid < 128) {
                int c4 = tid >> 3, g = tid & 7;        // row-group slow, k-group fast
                short* d = &As[(c4 * 4) * 40 + g * 4];
                if (ATRBF16) {
                    const short* src = (const short*)Au + (long)(ku + g * 4) * lda + m0 + c4 * 4;
                    short4 r0 = *(const short4*)(src);
                    short4 r1 = *(const short4*)(src + lda);
                    short4 r2 = *(const short4*)(src + 2 * lda);
                    short4 r3 = *(const short4*)(src + 3 * lda);
                    *(short4*)(d + 0 * 40) = make_short4(r0.x, r1.x, r2.x, r3.x);
                    *(short4*)(d + 1 * 40) = make_short4(r0.y, r1.y, r2.y, r3.y);
                    *(short4*)(d + 2 * 40) = make_short4(r0.z, r1.z, r2.z, r3.z);
                    *(short4*)(d + 3 * 40) = make_short4(r0.w, r1.w, r2.w, r3.w);
                } else {
                    const float* src = (const float*)Au + (long)(ku + g * 4) * lda + m0 + c4 * 4;
                    float4 r0 = *(const float4*)(src);
                    float4 r1 = *(const float4*)(src + lda);
                    float4 r2 = *(const float4*)(src + 2 * lda);
                    float4 r3 = *(const float4*)(src + 3 * lda);
                    *(short4*)(d + 0 * 40) = make_short4(f2bf(r0.x), f2bf(r1.x), f2bf(r2.x), f2bf(r3.x));
                    *(short4*)(d + 1 * 40) = make_short4(f2bf(r0.y), f2bf(r1.y), f2bf(r2.y), f2bf(r3.y));
                    *(short4*)(d + 2 * 40) = make_short4(f2bf(r0.z), f2bf(r1.z), f2bf(r2.z), f2bf(r3.z));
                    *(short4*)(d + 3 * 40) = make_short4(f2bf(r0.w), f2bf(r1.w), f2bf(r2.w), f2bf(r3.w));
                }
            }
        }
        if (TILE == 128 || tid < 128) {
            int c4 = tid >> 3, g = tid & 7;            // n-group slow, k-group fast
            short* d = &Bs[(c4 * 4) * 40 + g * 4];
            if (BBF16) {
                const short* src = (const short*)Bu + (long)(ku + g * 4) * ldb + n0 + c4 * 4;
                short4 r0 = *(const short4*)(src);
                short4 r1 = *(const short4*)(src + ldb);
                short4 r2 = *(const short4*)(src + 2 * ldb);
                short4 r3 = *(const short4*)(src + 3 * ldb);
                *(short4*)(d + 0 * 40) = make_short4(r0.x, r1.x, r2.x, r3.x);
                *(short4*)(d + 1 * 40) = make_short4(r0.y, r1.y, r2.y, r3.y);
                *(short4*)(d + 2 * 40) = make_short4(r0.z, r1.z, r2.z, r3.z);
                *(short4*)(d + 3 * 40) = make_short4(r0.w, r1.w, r2.w, r3.w);
            } else {
                const float* src = (const float*)Bu + (long)(ku + g * 4) * ldb + n0 + c4 * 4;
                float4 r0 = *(const float4*)(src);
                float4 r1 = *(const float4*)(src + ldb);
                float4 r2 = *(const float4*)(src + 2 * ldb);
                float4 r3 = *(const float4*)(src + 3 * ldb);
                *(short4*)(d + 0 * 40) = make_short4(f2bf(r0.x), f2bf(r1.x), f2bf(r2.x), f2bf(r3.x));
                *(short4*)(d + 1 * 40) = make_short4(f2bf(r0.y), f2bf(r1.y), f2bf(r2.y), f2bf(r3.y));
                *(short4*)(d + 2 * 40) = make_short4(f2bf(r0.z), f2bf(r1.z), f2bf(r2.z), f2bf(r3.z));
                *(short4*)(d + 3 * 40) = make_short4(f2bf(r0.w), f2bf(r1.w), f2bf(r2.w), f2bf(r3.w));
            }
        }
        __syncthreads();

        s16x8 af[WT], bf[WT];
#pragma unroll
        for (int t = 0; t < WT; ++t) {
            af[t] = *(const s16x8*)&As[(wrow * (TILE / 2) + t * 16 + lane16) * 40 + quad * 8];
            bf[t] = *(const s16x8*)&Bs[(wcol * (TILE / 2) + t * 16 + lane16) * 40 + quad * 8];
        }
#pragma unroll
        for (int i = 0; i < WT; ++i)
#pragma unroll
            for (int j = 0; j < WT; ++j)
                acc[i][j] = __builtin_amdgcn_mfma_f32_16x16x32_bf16(af[i], bf[j], acc[i][j], 0, 0, 0);
        __syncthreads();
    }

#pragma unroll
    for (int i = 0; i < WT; ++i) {
        int gm = m0 + wrow * (TILE / 2) + i * 16 + quad * 4;
#pragma unroll
        for (int j = 0; j < WT; ++j) {
            int gn = n0 + wcol * (TILE / 2) + j * 16 + lane16;
            float bv = bias ? bias[gn] : 0.f;
#pragma unroll
            for (int r = 0; r < 4; ++r) {
                float val = acc[i][j][r] + bv;
                if (RELU) val = fmaxf(val, 0.f);
                if (OBF16) Cs[(long)(gm + r) * ldc + gn] = f2bf(val);
                else       C[(long)(gm + r) * ldc + gn] = val;
            }
        }
    }
}

// ---------------------------------------------------------------------------
// BF16-input MFMA GEMM (TRANS_B — used for QK^T): C = scale*(A@B^T)
// ---------------------------------------------------------------------------
template <bool OBF16>
__global__ __launch_bounds__(256) void bgemm(const short* __restrict__ A,
                                             const short* __restrict__ B,
                                             void* __restrict__ Cv,
                                             float outscale,
                                             int M, int Nc, int K,
                                             int lda, int ldb, int ldc,
                                             long sA, long sB, long sC) {
    __shared__ __align__(16) short As[128 * 40];
    __shared__ __align__(16) short Bs[128 * 40];
    const int z = blockIdx.z;
    A += (long)z * sA;
    B += (long)z * sB;
    float* C = (float*)Cv + (OBF16 ? 0 : (long)z * sC);
    short* Cs = (short*)Cv + (OBF16 ? (long)z * sC : 0);
    const int m0 = blockIdx.y * 128, n0 = blockIdx.x * 128;
    const int tid = threadIdx.x;
    const int lane16 = tid & 15;
    const int quad = (tid & 63) >> 4;
    const int wrow = (tid >> 6) >> 1, wcol = (tid >> 6) & 1;

    f32x4 acc[4][4] = {};

    for (int k0 = 0; k0 < K; k0 += 32) {
#pragma unroll
        for (int p = 0; p < 2; ++p) {
            int u = tid + p * 256;
            int row = u >> 2, g = u & 3;
            *(s16x8*)&As[row * 40 + g * 8] =
                *(const s16x8*)(A + (long)(m0 + row) * lda + k0 + g * 8);
        }
#pragma unroll
        for (int p = 0; p < 2; ++p) {
            int u = tid + p * 256;
            int row = u >> 2, g = u & 3;
            *(s16x8*)&Bs[row * 40 + g * 8] =
                *(const s16x8*)(B + (long)(n0 + row) * ldb + k0 + g * 8);
        }
        __syncthreads();

        s16x8 af[4], bf[4];
#pragma unroll
        for (int t = 0; t < 4; ++t) {
            af[t] = *(const s16x8*)&As[(wrow * 64 + t * 16 + lane16) * 40 + quad * 8];
            bf[t] = *(const s16x8*)&Bs[(wcol * 64 + t * 16 + lane16) * 40 + quad * 8];
        }
#pragma unroll
        for (int i = 0; i < 4; ++i)
#pragma unroll
            for (int j = 0; j < 4; ++j)
                acc[i][j] = __builtin_amdgcn_mfma_f32_16x16x32_bf16(af[i], bf[j], acc[i][j], 0, 0, 0);
        __syncthreads();
    }

#pragma unroll
    for (int i = 0; i < 4; ++i) {
        int gm = m0 + wrow * 64 + i * 16 + quad * 4;
#pragma unroll
        for (int j = 0; j < 4; ++j) {
            int gn = n0 + wcol * 64 + j * 16 + lane16;
#pragma unroll
            for (int r = 0; r < 4; ++r) {
                float val = acc[i][j][r] * outscale;
                if (OBF16) Cs[(long)(gm + r) * ldc + gn] = f2bf(val);
                else       C[(long)(gm + r) * ldc + gn] = val;
            }
        }
    }
}

// ---------------------------------------------------------------------------
// FUSED edge-softmax + PV gather. 16 lanes/dst node, XCD-swizzled blocks.
// Phase 1 (lane-per-edge): logit from S + eattr·qWe, wv=exp; (src,wv) kept in
// registers for chunks<4 (deg<=64 common case; alpha spilled for overflow).
// Butterfly-reduce l and ea-moments. Phase 2: shfl-broadcast (src,wv), 16
// independent V loads per chunk. h = relu(acc/l + (ea5/l)@We + skip), bf16.
// ---------------------------------------------------------------------------
__global__ __launch_bounds__(256) void attn_pv_kernel(const short* __restrict__ S,
                                                      const int* __restrict__ ei,
                                                      const float* __restrict__ eattr,
                                                      const float* __restrict__ We,
                                                      const int* __restrict__ rp_dst,
                                                      const int* __restrict__ deg_dst,
                                                      const int* __restrict__ eid_dst,
                                                      const short* __restrict__ qkvs,
                                                      float* __restrict__ alpha,
                                                      short* __restrict__ h) {
    __shared__ float sWe[EDIM_ * 128];
    int g = threadIdx.x >> 4;
    int lane = threadIdx.x & 15;
    int gbase = (threadIdx.x & 63) & ~15;
    // XCD swizzle: graph's 32 blocks on one XCD
    int b = blockIdx.x;
    int xcd = b & 7, idx = b >> 3;
    int nb = (xcd * 8 + (idx >> 5)) * 32 + (idx & 31);
    int node = nb * 16 + g;
    for (int i = threadIdx.x; i < EDIM_ * 128; i += 256) sWe[i] = We[i];
    __syncthreads();

    // inline qWe: lane covers channels lane*8..+7, butterfly over 16 lanes
    float qw[EDIM_];
    {
        s16x8 qv = *(const s16x8*)(qkvs + (long)node * 512 + lane * 8);
        float qf[8];
#pragma unroll
        for (int j = 0; j < 8; ++j) qf[j] = bf2f(qv[j]);
#pragma unroll
        for (int d = 0; d < EDIM_; ++d) {
            float p = 0.f;
#pragma unroll
            for (int j = 0; j < 8; ++j) p += qf[j] * sWe[d * 128 + lane * 8 + j];
            qw[d] = p;
        }
#pragma unroll
        for (int off = 8; off; off >>= 1)
#pragma unroll
            for (int d = 0; d < EDIM_; ++d) qw[d] += __shfl_xor(qw[d], off);
#pragma unroll
        for (int d = 0; d < EDIM_; ++d) qw[d] *= 0.08838834764831845f;
    }

    int start = rp_dst[node], cnt = deg_dst[node];
    const short* Srow = S + (long)node * 512;
    int nch = (cnt + 15) >> 4;

    // ---- phase 1: per-edge softmax weights ----
    float lsum = 0.f, a5[EDIM_] = {};
    int   src_c[4] = {0, 0, 0, 0};
    float a_c[4]   = {0.f, 0.f, 0.f, 0.f};
    for (int c = 0; c < nch; ++c) {
        int t = c * 16 + lane;
        int src = 0; float wv = 0.f;
        if (t < cnt) {
            int e = eid_dst[start + t];
            src = ei[e];
            float lg = bf2f(Srow[src & 511]);
            float ea[EDIM_];
#pragma unroll
            for (int d = 0; d < EDIM_; ++d) { ea[d] = eattr[e * EDIM_ + d]; lg += ea[d] * qw[d]; }
            wv = expf(lg);                         // logits O(1): no max-pass needed
            lsum += wv;
#pragma unroll
            for (int d = 0; d < EDIM_; ++d) a5[d] += wv * ea[d];
        }
        if (c < 4) { src_c[c] = src; a_c[c] = wv; }
        else if (t < cnt) alpha[start + t] = wv;   // rare overflow spill (deg>64)
    }
#pragma unroll
    for (int off = 8; off; off >>= 1) {
        lsum += __shfl_xor(lsum, off);
#pragma unroll
        for (int d = 0; d < EDIM_; ++d) a5[d] += __shfl_xor(a5[d], off);
    }
    float inv = (lsum > 0.f) ? 1.f / lsum : 0.f;
    float e5[EDIM_];
#pragma unroll
    for (int d = 0; d < EDIM_; ++d) e5[d] = a5[d] * inv;

    // ---- phase 2: PV gather via shfl-broadcast of register-held (src,wv) ----
    float acc[8] = {};
    for (int c = 0; c < nch; ++c) {
        int src; float a;
        if (c < 4) { src = src_c[c]; a = a_c[c]; }
        else {
            int t = c * 16 + lane;
            if (t < cnt) {
                int e = eid_dst[start + t];
                src = ei[e];
                a = alpha[start + t];              // own-lane readback (coherent)
            } else { src = 0; a = 0.f; }
        }
        int m = min(16, cnt - c * 16);
        if (m == 16) {
#pragma unroll
            for (int j = 0; j < 16; ++j) {
                int   sj = __shfl(src, gbase + j);
                float aj = __shfl(a,   gbase + j);
                s16x8 v = *(const s16x8*)(qkvs + (long)sj * 512 + 256 + lane * 8);
#pragma unroll
                for (int k = 0; k < 8; ++k) acc[k] += aj * bf2f(v[k]);
            }
        } else {
            for (int j = 0; j < m; ++j) {
                int   sj = __shfl(src, gbase + j);
                float aj = __shfl(a,   gbase + j);
                s16x8 v = *(const s16x8*)(qkvs + (long)sj * 512 + 256 + lane * 8);
#pragma unroll
                for (int k = 0; k < 8; ++k) acc[k] += aj * bf2f(v[k]);
            }
        }
    }

    s16x8 sk = *(const s16x8*)(qkvs + (long)node * 512 + 384 + lane * 8);
    s16x8 o;
#pragma unroll
    for (int j = 0; j < 8; ++j) {
        float ec = 0.f;
#pragma unroll
        for (int d = 0; d < EDIM_; ++d) ec += e5[d] * sWe[d * 128 + lane * 8 + j];
        float val = acc[j] * inv + ec + bf2f(sk[j]);
        o[j] = f2bf(fmaxf(val, 0.f));
    }
    *(s16x8*)(h + (long)node * 128 + lane * 8) = o;
}

// ---------------------------------------------------------------------------
// Dense adjacency count build (uint8 per (src,dst)), by src-CSR.
// ---------------------------------------------------------------------------
__global__ __launch_bounds__(256) void adense_kernel(const int* __restrict__ ei,
                                                     const int* __restrict__ rp_src,
                                                     const int* __restrict__ deg_src,
                                                     const int* __restrict__ eid_src,
                                                     unsigned char* __restrict__ Adense) {
    __shared__ int rows[16][512];
    int g = threadIdx.x >> 4;
    int lane = threadIdx.x & 15;
    int node = blockIdx.x * 16 + g;
    int* row = rows[g];
    for (int i = lane; i < 512; i += 16) row[i] = 0;
    int start = rp_src[node], cnt = deg_src[node];
    for (int t = lane; t < cnt; t += 16) {
        int e = eid_src[start + t];
        int dst = ei[EDGES + e] & 511;
        atomicAdd(&row[dst], 1);
    }
    unsigned* Ar = (unsigned*)(Adense + (long)node * 512);
    for (int i = lane; i < 128; i += 16) {
        unsigned p = (unsigned)row[4 * i]
                   | ((unsigned)row[4 * i + 1] << 8)
                   | ((unsigned)row[4 * i + 2] << 16)
                   | ((unsigned)row[4 * i + 3] << 24);
        Ar[i] = p;
    }
}

// ---------------------------------------------------------------------------
// Row-wise softmax; IB: bf16 input, OB: bf16 output
// ---------------------------------------------------------------------------
template <int NC, bool IB, bool OB>
__global__ __launch_bounds__(256) void softmax_kernel(const void* __restrict__ inv_,
                                                      void* __restrict__ outv) {
    int wave = threadIdx.x >> 6;
    int lane = threadIdx.x & 63;
    int row = blockIdx.x * 4 + wave;
    constexpr int PER = NC / 64;
    float v[PER];
    float mx = -INFINITY;
    if (IB) {
        const short* p = (const short*)inv_ + (long)row * NC;
#pragma unroll
        for (int j = 0; j < PER; ++j) { v[j] = bf2f(p[lane + j * 64]); mx = fmaxf(mx, v[j]); }
    } else {
        const float* p = (const float*)inv_ + (long)row * NC;
#pragma unroll
        for (int j = 0; j < PER; ++j) { v[j] = p[lane + j * 64]; mx = fmaxf(mx, v[j]); }
    }
#pragma unroll
    for (int off = 32; off; off >>= 1) mx = fmaxf(mx, __shfl_xor(mx, off));
    float sm = 0.f;
#pragma unroll
    for (int j = 0; j < PER; ++j) { v[j] = expf(v[j] - mx); sm += v[j]; }
#pragma unroll
    for (int off = 32; off; off >>= 1) sm += __shfl_xor(sm, off);
    float inv = 1.f / sm;
    if (OB) {
        short* o = (short*)outv + (long)row * NC;
#pragma unroll
        for (int j = 0; j < PER; ++j) o[lane + j * 64] = f2bf(v[j] * inv);
    } else {
        float* o = (float*)outv + (long)row * NC;
#pragma unroll
        for (int j = 0; j < PER; ++j) o[lane + j * 64] = v[j] * inv;
    }
}

// ---------------------------------------------------------------------------
// Pooled-adj normalization
// ---------------------------------------------------------------------------
template <int KC>
__global__ __launch_bounds__(256) void dinv_kernel(const float* __restrict__ adj,
                                                   float* __restrict__ dinv) {
    int wave = threadIdx.x >> 6;
    int lane = threadIdx.x & 63;
    int row = blockIdx.x * 4 + wave;
    int b = row / KC, r = row % KC;
    const float* p = adj + (long)b * KC * KC + (long)r * KC;
    float s = 0.f;
    for (int j = lane; j < KC; j += 64)
        if (j != r) s += p[j];
#pragma unroll
    for (int off = 32; off; off >>= 1) s += __shfl_xor(s, off);
    if (lane == 0) dinv[row] = 1.f / (sqrtf(s) + 1e-15f);
}

template <int KC>
__global__ __launch_bounds__(256) void scale_adj_kernel(float* __restrict__ adj,
                                                        const float* __restrict__ dinv) {
    long i = (long)blockIdx.x * 256 + threadIdx.x;
    int c = (int)(i % KC);
    long t = i / KC;
    int r = (int)(t % KC);
    int b = (int)(t / KC);
    float v = adj[i];
    v = (r == c) ? 0.f : v * dinv[b * KC + r] * dinv[b * KC + c];
    adj[i] = v;
}

// ---------------------------------------------------------------------------
// Readout
// ---------------------------------------------------------------------------
__global__ __launch_bounds__(128) void readout_kernel(const float* __restrict__ xd3,
                                                      const float* __restrict__ W_lin1,
                                                      const float* __restrict__ b_lin1,
                                                      const float* __restrict__ W_ro,
                                                      const float* __restrict__ b_ro,
                                                      float* __restrict__ out) {
    int b = blockIdx.x, t = threadIdx.x;
    __shared__ float g[128], g2[128], wred[2];
    const float* X = xd3 + (long)b * K2C * 128;
    float s = 0.f;
    for (int r = 0; r < K2C; ++r) s += X[r * 128 + t];
    g[t] = s * (1.f / (float)K2C);
    __syncthreads();
    float u = b_lin1[t];
    for (int k = 0; k < 128; ++k) u += g[k] * W_lin1[k * 128 + t];
    g2[t] = fmaxf(u, 0.f);
    __syncthreads();
    float p = g2[t] * W_ro[t];
#pragma unroll
    for (int off = 32; off; off >>= 1) p += __shfl_xor(p, off);
    if ((t & 63) == 0) wred[t >> 6] = p;
    __syncthreads();
    if (t == 0) {
        float tot = wred[0] + wred[1] + b_ro[0];
        out[b] = 1.f / (1.f + expf(-tot));
    }
}

// ---------------------------------------------------------------------------
extern "C" void kernel_launch(void* const* d_in, const int* in_sizes, int n_in,
                              void* d_out, int out_size, void* d_ws, size_t ws_size,
                              hipStream_t stream) {
    const float* x      = (const float*)d_in[0];
    const int*   ei     = (const int*)d_in[1];
    const float* eattr  = (const float*)d_in[2];
    const float* gamma  = (const float*)d_in[4];
    const float* beta   = (const float*)d_in[5];
    const float* Wq     = (const float*)d_in[6];
    const float* bq     = (const float*)d_in[7];
    const float* Wk     = (const float*)d_in[8];
    const float* bk     = (const float*)d_in[9];
    const float* Wv     = (const float*)d_in[10];
    const float* bv     = (const float*)d_in[11];
    const float* We     = (const float*)d_in[12];
    const float* Wskip  = (const float*)d_in[13];
    const float* bskip  = (const float*)d_in[14];
    const float* W_mlp1 = (const float*)d_in[15];
    const float* b_mlp1 = (const float*)d_in[16];
    const float* W2_rel = (const float*)d_in[17];
    const float* b2_rel = (const float*)d_in[18];
    const float* W2_root= (const float*)d_in[19];
    const float* W_mlp2 = (const float*)d_in[20];
    const float* b_mlp2 = (const float*)d_in[21];
    const float* W3_rel = (const float*)d_in[22];
    const float* b3_rel = (const float*)d_in[23];
    const float* W3_root= (const float*)d_in[24];
    const float* W_lin1 = (const float*)d_in[25];
    const float* b_lin1 = (const float*)d_in[26];
    const float* W_ro   = (const float*)d_in[27];
    const float* b_ro   = (const float*)d_in[28];
    float* out = (float*)d_out;

    char* w = (char*)d_ws;
    const size_t MB = 1ull << 20;
    // Workspace (peak 110 MB), lifetime-aliased. Changes vs round 15:
    //   h → [80,88) (old Aden slot; free until adj1 at step 10b)
    //   Aden → [16,32) (over qkvs upper half, dead after fused attn_pv)
    //   xp1 GEMM reordered BEFORE adj1 GEMM (adj1 [80,96) clobbers h)
    short* qkvs = (short*)(w + 0);          // [NTOT,512] bf16 32MB (dead after step 6)
    short* s1fb = (short*)(w + 0);          // [NTOT,256] bf16 16MB (step 7, over dead qkvs lo)
    unsigned char* Aden = (unsigned char*)(w + 16 * MB);  // [NTOT,512] u8 16MB (over dead qkvs hi)
    short* S    = (short*)(w + 32 * MB);    // [NTOT,512] bf16 32MB (steps 5-6)
    short* T1s  = (short*)(w + 48 * MB);    // [NTOT,256] bf16 16MB (steps 8-9, over dead S hi)
    short* s1b  = (short*)(w + 64 * MB);    // [NTOT,256] bf16 16MB
    float* tgc2 = (float*)(w + 48 * MB);    // [B,256,128] fp32 8MB (step 11)
    short* xd2  = (short*)(w + 56 * MB);    // [B,256,128] bf16 4MB
    short* s2fb = (short*)(w + 64 * MB);    // [B,256,128] bf16 4MB
    short* s2b  = (short*)(w + 72 * MB);    // [B,256,128] bf16 4MB
    float* t2   = (float*)(w + 64 * MB);    // [B,256,128] fp32 8MB (over dead s2fb)
    float* adj2 = (float*)(w + 0);          // [B,128,128] 4MB
    float* xp2  = (float*)(w + 4 * MB);     // [B,128,128] 4MB
    float* t3   = (float*)(w + 8 * MB);     // [B,128,128] 4MB
    float* xd3  = (float*)(w + 12 * MB);    // [B,128,128] 4MB
    short* h    = (short*)(w + 80 * MB);    // [NTOT,128] bf16 8MB (steps 6-10a)
    float* adj1 = (float*)(w + 80 * MB);    // [B,256,256] 16MB (step 10b+, over dead h)
    float* xp1  = (float*)(w + 96 * MB);    // [B,256,128] 8MB
    float* alpha= (float*)(w + 97 * MB);    // [EDGES] fp32 2MB (overflow spill; dead before xp1... 
                                            //  xp1 written step 10a AFTER alpha dead at step 6) — 
                                            //  NOTE: alpha overlaps xp1 region; alpha dead after step 6, xp1 written step 10a. OK.
    char* misc  = w + 104 * MB;
    float* W4     = (float*)(misc + 0x00000);
    float* bias4  = (float*)(misc + 0x40000);
    float* scale  = (float*)(misc + 0x41400);
    float* shift  = (float*)(misc + 0x41600);
    float* dinv1  = (float*)(misc + 0x42000);
    float* dinv2  = (float*)(misc + 0x52000);
    int* deg_src  = (int*)(misc + 0x60000);
    int* deg_dst  = (int*)(misc + 0x80000);
    int* rp_src   = (int*)(misc + 0xA0000);
    int* rp_dst   = (int*)(misc + 0xC0000);
    int* cur_src  = (int*)(misc + 0xE0000);
    int* cur_dst  = (int*)(misc + 0x100000);
    int* eid_src  = (int*)(misc + 0x120000);
    int* eid_dst  = (int*)(misc + 0x320000);
    float* psum   = (float*)(misc + 0x520000);
    float* psq    = (float*)(misc + 0x540000);

    hipMemsetAsync(deg_src, 0, 2 * NTOT * sizeof(int), stream);

    // 1. BatchNorm affine params
    bn_stats_kernel<<<256, 256, 0, stream>>>(x, psum, psq);
    bn_finalize_kernel<<<1, 128, 0, stream>>>(psum, psq, gamma, beta, scale, shift);

    // 2. Pack fused qkvs weights
    pack_w4_kernel<<<256, 256, 0, stream>>>(Wq, Wk, Wv, Wskip, bq, bk, bv, bskip, W4, bias4);

    // 3. CSR by src and dst
    hist_kernel<<<EDGES / 256, 256, 0, stream>>>(ei, deg_src, deg_dst);
    scan2_kernel<<<2, 1024, 0, stream>>>(deg_src, rp_src, cur_src, deg_dst, rp_dst, cur_dst);
    scatter_kernel<<<EDGES / 256, 256, 0, stream>>>(ei, cur_src, cur_dst, eid_src, eid_dst);

    // 4. qkvs(bf16) = BN(x) @ [Wq|Wk|Wv|Wskip] + biases
    mgemm<128, false, true, false, false, true, false, false, false, false>
        <<<dim3(4, 256, 1), 256, 0, stream>>>(
        x, W4, nullptr, nullptr, 0, bias4, qkvs, scale, shift,
        NTOT, 512, 128, 128, 512, 512, 0, 0, 0);

    // 5. S(bf16) = (Q @ K^T) / sqrt(H) per graph (dense, MFMA)
    bgemm<true><<<dim3(4, 4, BGRAPH), 256, 0, stream>>>(
        qkvs + 0, qkvs + 128, S, 0.08838834764831845f,
        NNODE, NNODE, 128, 512, 512, 512,
        (long)NNODE * 512, (long)NNODE * 512, (long)NNODE * NNODE);

    // 6. FUSED edge-softmax + PV gather -> h(bf16)
    attn_pv_kernel<<<NTOT / 16, 256, 0, stream>>>(
        S, ei, eattr, We, rp_dst, deg_dst, eid_dst, qkvs, alpha, h);
    adense_kernel<<<NTOT / 16, 256, 0, stream>>>(ei, rp_src, deg_src, eid_src, Aden);

    // 7. s1fb(bf16) = h @ W_mlp1 + b ; s1b(bf16) = softmax(s1fb)
    mgemm<128, false, false, false, false, true, false, false, false, true>
        <<<dim3(2, 256, 1), 256, 0, stream>>>(
        h, W_mlp1, nullptr, nullptr, 0, b_mlp1, s1fb, nullptr, nullptr,
        NTOT, K1C, 128, 128, K1C, K1C, 0, 0, 0);
    softmax_kernel<K1C, true, true><<<NTOT / 4, 256, 0, stream>>>(s1fb, s1b);

    // 8. T1(bf16) = Adense(u8) @ s1b(bf16) — 128-tile (deep K, 512 blocks)
    mgemm<128, false, false, false, false, true, true, true, false, false>
        <<<dim3(2, 4, BGRAPH), 256, 0, stream>>>(
        Aden, s1b, nullptr, nullptr, 0, nullptr, T1s, nullptr, nullptr,
        NNODE, K1C, NNODE, NNODE, K1C, K1C,
        (long)NNODE * NNODE, (long)NNODE * K1C, (long)NNODE * K1C);

    // 9/10. xp1 = s1b^T h (64-tile, BEFORE adj1 clobbers h region) ;
    //       adj1 = s1b^T T1s — 128-tile
    mgemm<64, true, false, false, false, false, false, true, true, false>
        <<<dim3(2, 4, BGRAPH), 256, 0, stream>>>(
        s1b, h, nullptr, nullptr, 0, nullptr, xp1, nullptr, nullptr,
        K1C, 128, NNODE, K1C, 128, 128,
        (long)NNODE * K1C, (long)NNODE * 128, (long)K1C * 128);
    mgemm<128, true, false, false, false, false, false, true, true, false>
        <<<dim3(2, 2, BGRAPH), 256, 0, stream>>>(
        s1b, T1s, nullptr, nullptr, 0, nullptr, adj1, nullptr, nullptr,
        K1C, K1C, NNODE, K1C, K1C, K1C,
        (long)NNODE * K1C, (long)NNODE * K1C, (long)K1C * K1C);

    // 11. Normalize adj1
    dinv_kernel<K1C><<<(BGRAPH * K1C) / 4, 256, 0, stream>>>(adj1, dinv1);
    scale_adj_kernel<K1C><<<(BGRAPH * K1C * K1C) / 256, 256, 0, stream>>>(adj1, dinv1);

    // 12. GraphConv2: tgc2 = adj1@xp1 ; xd2(bf16) = relu([tgc2|xp1]@[W2_rel;W2_root]+b)
    mgemm<64, false, false, false, false, false, false, false, false, false>
        <<<dim3(2, 4, BGRAPH), 256, 0, stream>>>(
        adj1, xp1, nullptr, nullptr, 0, nullptr, tgc2, nullptr, nullptr,
        K1C, 128, K1C, K1C, 128, 128,
        (long)K1C * K1C, (long)K1C * 128, (long)K1C * 128);
    mgemm<64, false, false, true, true, true, false, false, false, false>
        <<<dim3(2, 256, 1), 256, 0, stream>>>(
        tgc2, W2_rel, xp1, W2_root, 128, b2_rel, xd2, nullptr, nullptr,
        BGRAPH * K1C, 128, 256, 128, 128, 128, 0, 0, 0);

    // 13. s2fb(bf16) = xd2 @ W_mlp2 + b ; s2b(bf16) = softmax(s2fb)
    mgemm<64, false, false, false, false, true, false, false, false, true>
        <<<dim3(2, 256, 1), 256, 0, stream>>>(
        xd2, W_mlp2, nullptr, nullptr, 0, b_mlp2, s2fb, nullptr, nullptr,
        BGRAPH * K1C, K2C, 128, 128, K2C, K2C, 0, 0, 0);
    softmax_kernel<K2C, true, true><<<(BGRAPH * K1C) / 4, 256, 0, stream>>>(s2fb, s2b);

    // 14. Pool2: t2 = adj1@s2b ; adj2 = s2b^T t2 ; xp2 = s2b^T xd2
    mgemm<64, false, false, false, false, false, false, true, false, false>
        <<<dim3(2, 4, BGRAPH), 256, 0, stream>>>(
        adj1, s2b, nullptr, nullptr, 0, nullptr, t2, nullptr, nullptr,
        K1C, K2C, K1C, K1C, K2C, K2C,
        (long)K1C * K1C, (long)K1C * K2C, (long)K1C * K2C);
    mgemm<64, true, false, false, false, false, false, false, true, false>
        <<<dim3(2, 2, BGRAPH), 256, 0, stream>>>(
        s2b, t2, nullptr, nullptr, 0, nullptr, adj2, nullptr, nullptr,
        K2C, K2C, K1C, K2C, K2C, K2C,
        (long)K1C * K2C, (long)K1C * K2C, (long)K2C * K2C);
    mgemm<64, true, false, false, false, false, false, true, true, false>
        <<<dim3(2, 2, BGRAPH), 256, 0, stream>>>(
        s2b, xd2, nullptr, nullptr, 0, nullptr, xp2, nullptr, nullptr,
        K2C, 128, K1C, K2C, 128, 128,
        (long)K1C * K2C, (long)K1C * 128, (long)K2C * 128);

    // 15. Normalize adj2
    dinv_kernel<K2C><<<(BGRAPH * K2C) / 4, 256, 0, stream>>>(adj2, dinv2);
    scale_adj_kernel<K2C><<<(BGRAPH * K2C * K2C) / 256, 256, 0, stream>>>(adj2, dinv2);

    // 16. GraphConv3: t3 = adj2@xp2 ; xd3 = [t3|xp2]@[W3_rel;W3_root] + b
    mgemm<64, false, false, false, false, false, false, false, false, false>
        <<<dim3(2, 2, BGRAPH), 256, 0, stream>>>(
        adj2, xp2, nullptr, nullptr, 0, nullptr, t3, nullptr, nullptr,
        K2C, 128, K2C, K2C, 128, 128,
        (long)K2C * K2C, (long)K2C * 128, (long)K2C * 128);
    mgemm<64, false, false, false, true, false, false, false, false, false>
        <<<dim3(2, 128, 1), 256, 0, stream>>>(
        t3, W3_rel, xp2, W3_root, 128, b3_rel, xd3, nullptr, nullptr,
        BGRAPH * K2C, 128, 256, 128, 128, 128, 0, 0, 0);

    // 17. Readout
    readout_kernel<<<BGRAPH, 128, 0, stream>>>(xd3, W_lin1, b_lin1, W_ro, b_ro, out);

    (void)in_sizes; (void)n_in; (void)out_size; (void)ws_size;
}